// Round 4
// baseline (2738.864 us; speedup 1.0000x reference)
//
#include <hip/hip_runtime.h>

#define K_ORDER 10
#define NFEAT 512
#define NHID 256
#define NOUT 64
#define PI_F 3.14159265358979323846f
#define SCAN_CHUNK 2048

typedef __bf16 bf16x8 __attribute__((ext_vector_type(8)));
typedef unsigned short ushort8 __attribute__((ext_vector_type(8)));
typedef float f32x4 __attribute__((ext_vector_type(4)));

__device__ __forceinline__ float bf2f(unsigned short u) {
    union { unsigned int i; float f; } x;
    x.i = ((unsigned int)u) << 16;
    return x.f;
}

__device__ __forceinline__ unsigned short f2bfu(float f) {
    __bf16 h = (__bf16)f;
    return *(unsigned short*)&h;
}

// ---------------- input dtype detection ----------------
__global__ void detect_kernel(const unsigned short* __restrict__ temp, int* __restrict__ flag) {
    if (threadIdx.x == 0 && blockIdx.x == 0) {
        int cnt = 0;
        for (int i = 0; i < K_ORDER + 1; ++i) {
            unsigned short s = temp[i];
            if (s >= 0x3E00 && s < 0x4080) cnt++;
        }
        flag[0] = (cnt >= 9) ? 1 : 0;
    }
}

// ---------------- graph preprocessing ----------------

__global__ void count_deg_kernel(const int* __restrict__ row, int* __restrict__ deg, int e) {
    int i = blockIdx.x * blockDim.x + threadIdx.x;
    if (i < e) atomicAdd(&deg[row[i]], 1);
}

__global__ void dinv_kernel(const int* __restrict__ deg, float* __restrict__ dinv, int n) {
    int i = blockIdx.x * blockDim.x + threadIdx.x;
    if (i < n) {
        int d = deg[i];
        dinv[i] = (d > 0) ? rsqrtf((float)d) : 0.0f;
    }
}

__global__ __launch_bounds__(256) void partial_sum_kernel(const int* __restrict__ deg,
                                                          int* __restrict__ bsum, int n) {
    __shared__ int ws[4];
    int b = blockIdx.x, t = threadIdx.x;
    int base = b * SCAN_CHUNK + t * 8;
    int s = 0;
    #pragma unroll
    for (int j = 0; j < 8; ++j) { int i = base + j; if (i < n) s += deg[i]; }
    #pragma unroll
    for (int m = 1; m < 64; m <<= 1) s += __shfl_xor(s, m, 64);
    if ((t & 63) == 0) ws[t >> 6] = s;
    __syncthreads();
    if (t == 0) bsum[b] = ws[0] + ws[1] + ws[2] + ws[3];
}

// 1 block, 64 threads; nb <= 64
__global__ void scan_small_kernel(const int* __restrict__ bsum, int* __restrict__ boff,
                                  int* __restrict__ rowptr, int nb, int n) {
    int t = threadIdx.x;
    int v = (t < nb) ? bsum[t] : 0;
    int x = v;
    #pragma unroll
    for (int m = 1; m < 64; m <<= 1) { int y = __shfl_up(x, m, 64); if (t >= m) x += y; }
    if (t < nb) boff[t] = x - v;
    if (t == 63) rowptr[n] = x;
}

__global__ __launch_bounds__(256) void scan_apply_kernel(const int* __restrict__ deg,
                                                         const int* __restrict__ boff,
                                                         int* __restrict__ rowptr,
                                                         int* __restrict__ cursor, int n) {
    __shared__ int wtot[4];
    __shared__ int woff_s[4];
    int b = blockIdx.x, t = threadIdx.x;
    int lane = t & 63, wid = t >> 6;
    int base = b * SCAN_CHUNK + t * 8;
    int v[8], s[8];
    int run = 0;
    #pragma unroll
    for (int j = 0; j < 8; ++j) {
        int i = base + j;
        v[j] = (i < n) ? deg[i] : 0;
        run += v[j];
        s[j] = run;
    }
    int tsum = run;
    int x = tsum;
    #pragma unroll
    for (int m = 1; m < 64; m <<= 1) { int y = __shfl_up(x, m, 64); if (lane >= m) x += y; }
    int texcl = x - tsum;
    if (lane == 63) wtot[wid] = x;
    __syncthreads();
    if (t == 0) {
        int r = 0;
        #pragma unroll
        for (int w = 0; w < 4; ++w) { woff_s[w] = r; r += wtot[w]; }
    }
    __syncthreads();
    int ebase = boff[b] + woff_s[wid] + texcl;
    #pragma unroll
    for (int j = 0; j < 8; ++j) {
        int i = base + j;
        if (i < n) { int ex = ebase + s[j] - v[j]; rowptr[i] = ex; cursor[i] = ex; }
    }
}

__global__ void scatter_kernel(const int* __restrict__ row, const int* __restrict__ col,
                               int* __restrict__ cursor, int* __restrict__ cols_s, int e) {
    int i = blockIdx.x * blockDim.x + threadIdx.x;
    if (i < e) {
        int p = atomicAdd(&cursor[row[i]], 1);
        cols_s[p] = col[i];
    }
}

// ---------------- Chebyshev coefficients ----------------

__global__ void coef_kernel(const void* __restrict__ temp, const int* __restrict__ flag,
                            float* __restrict__ coe) {
    int i = threadIdx.x;
    bool isbf = flag[0] != 0;
    if (i <= K_ORDER) {
        float s = 0.0f;
        #pragma unroll
        for (int j = 0; j <= K_ORDER; ++j) {
            float t = isbf ? bf2f(((const unsigned short*)temp)[j]) : ((const float*)temp)[j];
            t = fmaxf(t, 0.0f);
            float theta = ((float)(K_ORDER - j) + 0.5f) * PI_F / (float)(K_ORDER + 1);
            s += cosf((float)i * theta) * t;
        }
        coe[i] = (2.0f / (float)(K_ORDER + 1)) * s;
    }
}

// ---------------- MFMA GEMM (round-1 verified version, verbatim) ----------------

template<int BN, bool RELU, bool A_FLAGGED>
__global__ __launch_bounds__(256) void gemm_kernel(const void* __restrict__ A,
                                                   const void* __restrict__ B,
                                                   const void* __restrict__ bias,
                                                   const int* __restrict__ flag,
                                                   unsigned short* __restrict__ C,
                                                   int M, int Kdim, int ldc) {
    constexpr int BM = 128, BK = 32;
    constexpr int FN = BN / 32;
    constexpr int LDT = BK + 8;
    __shared__ unsigned short lds_a[BM * LDT] __attribute__((aligned(16)));
    __shared__ unsigned short lds_b[BN * LDT] __attribute__((aligned(16)));

    const bool isbf = flag[0] != 0;
    int tid = threadIdx.x;
    int lane = tid & 63, wid = tid >> 6;
    int row0 = blockIdx.x * BM;
    int col0 = blockIdx.y * BN;
    int wrow = (wid >> 1) * (BM / 2);
    int wcol = (wid & 1) * (BN / 2);

    f32x4 acc[4][FN] = {};

    for (int k0 = 0; k0 < Kdim; k0 += BK) {
        #pragma unroll
        for (int it = 0; it < (BM * BK / 8) / 256; ++it) {
            int idx = it * 256 + tid;
            int r = idx >> 2;
            int kc = (idx & 3) * 8;
            int gr = row0 + r; if (gr >= M) gr = M - 1;
            size_t base = (size_t)gr * Kdim + k0 + kc;
            if (!A_FLAGGED || isbf) {
                *(ushort8*)&lds_a[r * LDT + kc] = *(const ushort8*)((const unsigned short*)A + base);
            } else {
                const float* Af = (const float*)A;
                f32x4 lo = *(const f32x4*)(Af + base);
                f32x4 hi = *(const f32x4*)(Af + base + 4);
                bf16x8 v;
                #pragma unroll
                for (int j = 0; j < 4; ++j) { v[j] = (__bf16)lo[j]; v[j + 4] = (__bf16)hi[j]; }
                *(bf16x8*)&lds_a[r * LDT + kc] = v;
            }
        }
        #pragma unroll
        for (int it = 0; it < (BN * BK / 8) / 256; ++it) {
            int idx = it * 256 + tid;
            int r = idx >> 2;
            int kc = (idx & 3) * 8;
            size_t base = (size_t)(col0 + r) * Kdim + k0 + kc;
            if (isbf) {
                *(ushort8*)&lds_b[r * LDT + kc] = *(const ushort8*)((const unsigned short*)B + base);
            } else {
                const float* Bf = (const float*)B;
                f32x4 lo = *(const f32x4*)(Bf + base);
                f32x4 hi = *(const f32x4*)(Bf + base + 4);
                bf16x8 v;
                #pragma unroll
                for (int j = 0; j < 4; ++j) { v[j] = (__bf16)lo[j]; v[j + 4] = (__bf16)hi[j]; }
                *(bf16x8*)&lds_b[r * LDT + kc] = v;
            }
        }
        __syncthreads();

        int kq = (lane >> 4) * 8;
        bf16x8 af[4];
        bf16x8 bfr[FN];
        #pragma unroll
        for (int mi = 0; mi < 4; ++mi)
            af[mi] = *(bf16x8*)&lds_a[(wrow + mi * 16 + (lane & 15)) * LDT + kq];
        #pragma unroll
        for (int ni = 0; ni < FN; ++ni)
            bfr[ni] = *(bf16x8*)&lds_b[(wcol + ni * 16 + (lane & 15)) * LDT + kq];
        #pragma unroll
        for (int mi = 0; mi < 4; ++mi)
            #pragma unroll
            for (int ni = 0; ni < FN; ++ni)
                acc[mi][ni] = __builtin_amdgcn_mfma_f32_16x16x32_bf16(af[mi], bfr[ni],
                                                                      acc[mi][ni], 0, 0, 0);
        __syncthreads();
    }

    #pragma unroll
    for (int mi = 0; mi < 4; ++mi) {
        #pragma unroll
        for (int ni = 0; ni < FN; ++ni) {
            #pragma unroll
            for (int rg = 0; rg < 4; ++rg) {
                int grow = row0 + wrow + mi * 16 + (lane >> 4) * 4 + rg;
                int gcol = col0 + wcol + ni * 16 + (lane & 15);
                if (grow < M) {
                    float bb = isbf ? bf2f(((const unsigned short*)bias)[gcol])
                                    : ((const float*)bias)[gcol];
                    float vv = acc[mi][ni][rg] + bb;
                    if (RELU) vv = fmaxf(vv, 0.0f);
                    __bf16 h = (__bf16)vv;
                    C[(size_t)grow * ldc + gcol] = *(unsigned short*)&h;
                }
            }
        }
    }
}

// ---------------- row-major [N][64] -> slice-major [4][N][16] permute ----------------
__global__ void slice_kernel(const unsigned short* __restrict__ in,
                             unsigned short* __restrict__ out, int n) {
    int idx = blockIdx.x * blockDim.x + threadIdx.x;   // (row, slice) pairs
    if (idx >= n * 4) return;
    int r = idx >> 2, s = idx & 3;
    ushort8 a = *(const ushort8*)(in + (size_t)r * 64 + s * 16);
    ushort8 b = *(const ushort8*)(in + (size_t)r * 64 + s * 16 + 8);
    unsigned short* dst = out + ((size_t)s * n + r) * 16;
    *(ushort8*)dst = a;
    *(ushort8*)(dst + 8) = b;
}

// ---------------- Chebyshev propagation, feature-sliced for per-XCD L2 residency ----
// Tx buffers + outacc are SLICE-MAJOR [4][N][16]: per-slice gather table = N*32B =
// 3.2MB < 4MB per-XCD L2. 1-D grid; s = bid & 3 so round-robin XCD assignment
// (bid % 8) gives each XCD exactly one slice -> its gathers stay L2-resident.
// Wave per (row, slice): lane = (sub=lane>>1 edge slot of 32, fc=lane&1 feat-half).
// P[r] = -dinv[r] * sum_edges dinv[c] * v[c]
// mode 0: tdst = P ; outacc = coe0/2 * vsrc[own] + coe1 * P
// mode 1: t2 = 2P - tdst[own]; tdst[own] = t2; outacc += coe[ci] * t2

__global__ __launch_bounds__(256) void prop_kernel(
    const unsigned short* __restrict__ vsrc,   // [4][n][16] bf16
    unsigned short* __restrict__ tdst,         // [4][n][16] bf16
    float* __restrict__ outacc,                // [4][n][16] f32
    const int* __restrict__ rowptr, const int* __restrict__ cols,
    const float* __restrict__ dinv, const float* __restrict__ coe,
    int mode, int ci, int n)
{
    const int bid = blockIdx.x;
    const int s = bid & 3;
    const int lane = threadIdx.x & 63;
    const int r = (bid >> 2) * 4 + (threadIdx.x >> 6);
    if (r >= n) return;
    const unsigned short* ts = vsrc + (size_t)s * n * 16;
    unsigned short* td = tdst + (size_t)s * n * 16;
    float* oa = outacc + (size_t)s * n * 16;

    const int fc = lane & 1;
    const int sub = lane >> 1;
    const int e0 = rowptr[r], e1 = rowptr[r + 1];
    float acc[8] = {};
    for (int e = e0; e < e1; e += 32) {
        int ee = e + sub;
        bool valid = ee < e1;
        int c = valid ? cols[ee] : 0;
        float w = valid ? dinv[c] : 0.0f;
        ushort8 vv = *(const ushort8*)&ts[(size_t)c * 16 + fc * 8];
        #pragma unroll
        for (int j = 0; j < 8; ++j)
            acc[j] = fmaf(w, bf2f(vv[j]), acc[j]);
    }
    // reduce over sub (lane bits 1..5); lanes sharing bit0 (fc) combine
    #pragma unroll
    for (int m = 2; m < 64; m <<= 1)
        #pragma unroll
        for (int j = 0; j < 8; ++j)
            acc[j] += __shfl_xor(acc[j], m, 64);

    if (lane < 2) {     // lane 0: feats 0..7 of slice, lane 1: feats 8..15
        float dr = -dinv[r];
        size_t tbase = (size_t)r * 16 + lane * 8;
        float P[8];
        #pragma unroll
        for (int j = 0; j < 8; ++j) P[j] = dr * acc[j];
        if (mode == 0) {
            ushort8 v0 = *(const ushort8*)&ts[tbase];
            ushort8 hout;
            #pragma unroll
            for (int j = 0; j < 8; ++j) hout[j] = f2bfu(P[j]);
            *(ushort8*)&td[tbase] = hout;
            float c0 = coe[0] * 0.5f, c1 = coe[1];
            #pragma unroll
            for (int j = 0; j < 8; ++j)
                oa[tbase + j] = c0 * bf2f(v0[j]) + c1 * P[j];
        } else {
            ushort8 t0v = *(const ushort8*)&td[tbase];
            ushort8 hout;
            float cc = coe[ci];
            #pragma unroll
            for (int j = 0; j < 8; ++j) {
                float t2 = 2.0f * P[j] - bf2f(t0v[j]);
                hout[j] = f2bfu(t2);
                oa[tbase + j] += cc * t2;
            }
            *(ushort8*)&td[tbase] = hout;
        }
    }
}

// ---------------- slice-major -> row-major output convert ----------------
// NOTE: n is the NODE count (slice-major stride), NOT the element count.
__global__ void convert_kernel(const float* __restrict__ in, const int* __restrict__ flag,
                               void* __restrict__ out, int n) {
    int idx = blockIdx.x * blockDim.x + threadIdx.x;   // (row, slice) pairs
    if (idx >= n * 4) return;
    int r = idx >> 2, s = idx & 3;
    const float* src = in + ((size_t)s * n + r) * 16;
    bool isbf = flag[0] != 0;
    if (!isbf) {
        float* dst = (float*)out + (size_t)r * 64 + s * 16;
        #pragma unroll
        for (int q = 0; q < 4; ++q)
            *(f32x4*)(dst + q * 4) = *(const f32x4*)(src + q * 4);
    } else {
        unsigned short* dst = (unsigned short*)out + (size_t)r * 64 + s * 16;
        ushort8 a, b;
        #pragma unroll
        for (int j = 0; j < 8; ++j) a[j] = f2bfu(src[j]);
        #pragma unroll
        for (int j = 0; j < 8; ++j) b[j] = f2bfu(src[8 + j]);
        *(ushort8*)dst = a;
        *(ushort8*)(dst + 8) = b;
    }
}

// ---------------- launch ----------------

extern "C" void kernel_launch(void* const* d_in, const int* in_sizes, int n_in,
                              void* d_out, int out_size, void* d_ws, size_t ws_size,
                              hipStream_t stream) {
    const void* feature = d_in[0];
    const void* W1      = d_in[1];
    const void* b1      = d_in[2];
    const void* W2      = d_in[3];
    const void* b2      = d_in[4];
    const void* temp    = d_in[5];
    const int* edge_index = (const int*)d_in[6];

    const int N = in_sizes[0] / NFEAT;   // 100000
    const int E = in_sizes[6] / 2;       // 3200000
    const int* row = edge_index;
    const int* col = edge_index + E;
    const int nb = (N + SCAN_CHUNK - 1) / SCAN_CHUNK;   // 49

    char* base = (char*)d_ws;
    size_t off = 0;
    auto alloc = [&](size_t bytes) -> char* {
        char* p = base + off;
        off = (off + bytes + 255) & ~(size_t)255;
        return p;
    };
    int*   flag   = (int*)  alloc(4);
    float* coe    = (float*)alloc(64);
    int*   bsum   = (int*)  alloc(256);
    int*   boff   = (int*)  alloc(256);
    float* dinv   = (float*)alloc((size_t)N * 4);
    int*   deg    = (int*)  alloc((size_t)N * 4);
    int*   rowptr = (int*)  alloc((size_t)(N + 1) * 4);
    int*   cursor = (int*)  alloc((size_t)(N + 1) * 4);
    // overlay region R: xhid (N*NHID*2 = 51.2MB) lives gemm1->gemm2;
    // afterwards colss (E*4 = 12.8MB) | outacc (N*NOUT*4 = 25.6MB slice-major) live there.
    char*  R      = alloc((size_t)N * NHID * 2);
    unsigned short* xhid = (unsigned short*)R;
    int*   colss  = (int*)R;
    float* outacc = (float*)(R + (size_t)E * 4);
    unsigned short* t_a = (unsigned short*)alloc((size_t)N * NOUT * 2);
    unsigned short* t_b = (unsigned short*)alloc((size_t)N * NOUT * 2);

    // dtype flag + coefficients
    detect_kernel<<<1, 64, 0, stream>>>((const unsigned short*)temp, flag);
    coef_kernel<<<1, 64, 0, stream>>>(temp, flag, coe);

    // dense MLP: gemm1 -> xhid, gemm2 -> t_b (row-major Tx0), then permute to
    // slice-major t_a. (t_b's row-major copy is dead after slice_kernel and is
    // reused as the mode-0 destination.)
    gemm_kernel<128, true, true><<<dim3((N + 127) / 128, NHID / 128), 256, 0, stream>>>(
        feature, W1, b1, flag, xhid, N, NFEAT, NHID);
    gemm_kernel<64, false, false><<<dim3((N + 127) / 128, 1), 256, 0, stream>>>(
        xhid, W2, b2, flag, t_b, N, NHID, NOUT);
    slice_kernel<<<(N * 4 + 255) / 256, 256, 0, stream>>>(t_b, t_a, N);

    // graph preprocessing (xhid dead now; colss/outacc overlay it)
    hipMemsetAsync(deg, 0, (size_t)N * 4, stream);
    count_deg_kernel<<<(E + 255) / 256, 256, 0, stream>>>(row, deg, E);
    dinv_kernel<<<(N + 255) / 256, 256, 0, stream>>>(deg, dinv, N);
    partial_sum_kernel<<<nb, 256, 0, stream>>>(deg, bsum, N);
    scan_small_kernel<<<1, 64, 0, stream>>>(bsum, boff, rowptr, nb, N);
    scan_apply_kernel<<<nb, 256, 0, stream>>>(deg, boff, rowptr, cursor, N);
    scatter_kernel<<<(E + 255) / 256, 256, 0, stream>>>(row, col, cursor, colss, E);

    // Chebyshev propagation: 1-D grid over (row-quad, slice); slice = bid & 3
    int pgrid = ((N + 3) / 4) * 4;
    prop_kernel<<<pgrid, 256, 0, stream>>>(t_a, t_b, outacc, rowptr, colss, dinv, coe, 0, 0, N);
    unsigned short* src = t_b;
    unsigned short* dst = t_a;
    for (int i = 2; i <= K_ORDER; ++i) {
        prop_kernel<<<pgrid, 256, 0, stream>>>(src, dst, outacc, rowptr, colss, dinv, coe, 1, i, N);
        unsigned short* tmp = src; src = dst; dst = tmp;
    }

    convert_kernel<<<(N * 4 + 255) / 256, 256, 0, stream>>>(outacc, flag, d_out, N);
}

// Round 5
// 1541.582 us; speedup vs baseline: 1.7767x; 1.7767x over previous
//
#include <hip/hip_runtime.h>

#define K_ORDER 10
#define NFEAT 512
#define NHID 256
#define NOUT 64
#define PI_F 3.14159265358979323846f
#define SCAN_CHUNK 2048

typedef __bf16 bf16x8 __attribute__((ext_vector_type(8)));
typedef unsigned short ushort8 __attribute__((ext_vector_type(8)));
typedef float f32x4 __attribute__((ext_vector_type(4)));

__device__ __forceinline__ float bf2f(unsigned short u) {
    union { unsigned int i; float f; } x;
    x.i = ((unsigned int)u) << 16;
    return x.f;
}

__device__ __forceinline__ unsigned short f2bfu(float f) {
    __bf16 h = (__bf16)f;
    return *(unsigned short*)&h;
}

#define GLOAD_LDS16(g, l) __builtin_amdgcn_global_load_lds( \
    (const __attribute__((address_space(1))) void*)(g),     \
    (__attribute__((address_space(3))) void*)(l), 16, 0, 0)

// ---------------- input dtype detection ----------------
__global__ void detect_kernel(const unsigned short* __restrict__ temp, int* __restrict__ flag) {
    if (threadIdx.x == 0 && blockIdx.x == 0) {
        int cnt = 0;
        for (int i = 0; i < K_ORDER + 1; ++i) {
            unsigned short s = temp[i];
            if (s >= 0x3E00 && s < 0x4080) cnt++;
        }
        flag[0] = (cnt >= 9) ? 1 : 0;
    }
}

// ---------------- weight canonicalization (bf16 W, f32 bias) ----------------
__global__ void prep_weights(const void* __restrict__ W1, const void* __restrict__ b1,
                             const void* __restrict__ W2, const void* __restrict__ b2,
                             const int* __restrict__ flag,
                             unsigned short* __restrict__ w1o, float* __restrict__ b1o,
                             unsigned short* __restrict__ w2o, float* __restrict__ b2o) {
    bool isbf = flag[0] != 0;
    int stride = gridDim.x * blockDim.x;
    int i0 = blockIdx.x * blockDim.x + threadIdx.x;
    const int n1 = NHID * NFEAT;
    const int n2 = NOUT * NHID;
    for (int i = i0; i < n1; i += stride)
        w1o[i] = isbf ? ((const unsigned short*)W1)[i] : f2bfu(((const float*)W1)[i]);
    for (int i = i0; i < n2; i += stride)
        w2o[i] = isbf ? ((const unsigned short*)W2)[i] : f2bfu(((const float*)W2)[i]);
    for (int i = i0; i < NHID; i += stride)
        b1o[i] = isbf ? bf2f(((const unsigned short*)b1)[i]) : ((const float*)b1)[i];
    for (int i = i0; i < NOUT; i += stride)
        b2o[i] = isbf ? bf2f(((const unsigned short*)b2)[i]) : ((const float*)b2)[i];
}

// ---------------- graph preprocessing (round-0 verified, verbatim) ----------------

__global__ void count_deg_kernel(const int* __restrict__ row, int* __restrict__ deg, int e) {
    int i = blockIdx.x * blockDim.x + threadIdx.x;
    if (i < e) atomicAdd(&deg[row[i]], 1);
}

__global__ void dinv_kernel(const int* __restrict__ deg, float* __restrict__ dinv, int n) {
    int i = blockIdx.x * blockDim.x + threadIdx.x;
    if (i < n) {
        int d = deg[i];
        dinv[i] = (d > 0) ? rsqrtf((float)d) : 0.0f;
    }
}

__global__ __launch_bounds__(256) void partial_sum_kernel(const int* __restrict__ deg,
                                                          int* __restrict__ bsum, int n) {
    __shared__ int ws[4];
    int b = blockIdx.x, t = threadIdx.x;
    int base = b * SCAN_CHUNK + t * 8;
    int s = 0;
    #pragma unroll
    for (int j = 0; j < 8; ++j) { int i = base + j; if (i < n) s += deg[i]; }
    #pragma unroll
    for (int m = 1; m < 64; m <<= 1) s += __shfl_xor(s, m, 64);
    if ((t & 63) == 0) ws[t >> 6] = s;
    __syncthreads();
    if (t == 0) bsum[b] = ws[0] + ws[1] + ws[2] + ws[3];
}

// 1 block, 64 threads; nb <= 64
__global__ void scan_small_kernel(const int* __restrict__ bsum, int* __restrict__ boff,
                                  int* __restrict__ rowptr, int nb, int n) {
    int t = threadIdx.x;
    int v = (t < nb) ? bsum[t] : 0;
    int x = v;
    #pragma unroll
    for (int m = 1; m < 64; m <<= 1) { int y = __shfl_up(x, m, 64); if (t >= m) x += y; }
    if (t < nb) boff[t] = x - v;
    if (t == 63) rowptr[n] = x;
}

__global__ __launch_bounds__(256) void scan_apply_kernel(const int* __restrict__ deg,
                                                         const int* __restrict__ boff,
                                                         int* __restrict__ rowptr,
                                                         int* __restrict__ cursor, int n) {
    __shared__ int wtot[4];
    __shared__ int woff_s[4];
    int b = blockIdx.x, t = threadIdx.x;
    int lane = t & 63, wid = t >> 6;
    int base = b * SCAN_CHUNK + t * 8;
    int v[8], s[8];
    int run = 0;
    #pragma unroll
    for (int j = 0; j < 8; ++j) {
        int i = base + j;
        v[j] = (i < n) ? deg[i] : 0;
        run += v[j];
        s[j] = run;
    }
    int tsum = run;
    int x = tsum;
    #pragma unroll
    for (int m = 1; m < 64; m <<= 1) { int y = __shfl_up(x, m, 64); if (lane >= m) x += y; }
    int texcl = x - tsum;
    if (lane == 63) wtot[wid] = x;
    __syncthreads();
    if (t == 0) {
        int r = 0;
        #pragma unroll
        for (int w = 0; w < 4; ++w) { woff_s[w] = r; r += wtot[w]; }
    }
    __syncthreads();
    int ebase = boff[b] + woff_s[wid] + texcl;
    #pragma unroll
    for (int j = 0; j < 8; ++j) {
        int i = base + j;
        if (i < n) { int ex = ebase + s[j] - v[j]; rowptr[i] = ex; cursor[i] = ex; }
    }
}

__global__ void scatter_kernel(const int* __restrict__ row, const int* __restrict__ col,
                               int* __restrict__ cursor, int* __restrict__ cols_s, int e) {
    int i = blockIdx.x * blockDim.x + threadIdx.x;
    if (i < e) {
        int p = atomicAdd(&cursor[row[i]], 1);
        cols_s[p] = col[i];
    }
}

// ---------------- Chebyshev coefficients ----------------

__global__ void coef_kernel(const void* __restrict__ temp, const int* __restrict__ flag,
                            float* __restrict__ coe) {
    int i = threadIdx.x;
    bool isbf = flag[0] != 0;
    if (i <= K_ORDER) {
        float s = 0.0f;
        #pragma unroll
        for (int j = 0; j <= K_ORDER; ++j) {
            float t = isbf ? bf2f(((const unsigned short*)temp)[j]) : ((const float*)temp)[j];
            t = fmaxf(t, 0.0f);
            float theta = ((float)(K_ORDER - j) + 0.5f) * PI_F / (float)(K_ORDER + 1);
            s += cosf((float)i * theta) * t;
        }
        coe[i] = (2.0f / (float)(K_ORDER + 1)) * s;
    }
}

// ---------------- MFMA GEMM: global_load_lds staging + 2-phase pipeline ----------------
// (Round-2 GEMM; forensically validated: round-2 vs round-3 produced bit-identical
// outputs, and the round-2/3 failure was isolated to the convert_kernel arg bug.)
// A: runtime f32-or-bf16 when A_FLAGGED; B: canonical bf16; bias: canonical f32.
// Swizzle (rule #21, both-sides involution): linear LDS dest (HW requirement),
// inverse-swizzled per-lane GLOBAL source, same XOR applied on ds_read.
// One __syncthreads per K-step; next tile's loads issued before current compute.

template<int BN, int NBY, bool RELU, bool A_FLAGGED>
__global__ __launch_bounds__(256) void gemm_kernel(
    const void* __restrict__ A, const unsigned short* __restrict__ Bw,
    const float* __restrict__ bias, const int* __restrict__ flag,
    unsigned short* __restrict__ C, int M, int Kdim, int ldc)
{
    constexpr int BM = 128, BK = 32;
    constexpr int FN = BN / 32;
    constexpr int ABUF = A_FLAGGED ? (BM * BK * 4) : (BM * BK * 2);
    constexpr int BBUF = BN * BK * 2;
    __shared__ char lds[2 * ABUF + 2 * BBUF] __attribute__((aligned(16)));

    const int tid = threadIdx.x;
    const int lane = tid & 63, wid = tid >> 6;
    const int bid = blockIdx.x;
    const int by = bid % NBY;        // col-blocks dispatch-adjacent for A reuse
    const int bx = bid / NBY;
    const int row0 = bx * BM;
    const int col0 = by * BN;
    const int wrow = (wid >> 1) * (BM / 2);
    const int wcol = (wid & 1) * (BN / 2);
    const bool af32 = A_FLAGGED ? (flag[0] == 0) : false;

    char* ldsA0 = lds;
    char* ldsB0 = lds + 2 * ABUF;

    auto stage = [&](int buf, int k0) {
        {   // B tile [BN][BK] bf16, 64B rows, chunk swizzle mask (row&3)
            constexpr int PW = (BBUF / 1024) / 4;   // 2 (BN=128) or 1 (BN=64)
            #pragma unroll
            for (int rr = 0; rr < PW; ++rr) {
                int q = rr * 4 + wid;
                int off = q * 1024 + lane * 16;
                int brow = off >> 6;
                int scol = ((off >> 4) & 3) ^ (brow & 3);
                const char* src = (const char*)Bw + (((size_t)(col0 + brow) * Kdim + k0) << 1) + scol * 16;
                GLOAD_LDS16(src, ldsB0 + buf * BBUF + q * 1024);
            }
        }
        if (af32) {         // A tile [128][32] f32, 128B rows, chunk swizzle mask (row&7)
            #pragma unroll
            for (int rr = 0; rr < 4; ++rr) {
                int q = rr * 4 + wid;
                int off = q * 1024 + lane * 16;
                int arow = off >> 7;
                int scol = ((off >> 4) & 7) ^ (arow & 7);
                int grow = row0 + arow; if (grow >= M) grow = M - 1;
                const char* src = (const char*)A + (((size_t)grow * Kdim + k0) << 2) + scol * 16;
                GLOAD_LDS16(src, ldsA0 + buf * ABUF + q * 1024);
            }
        } else {            // A tile [128][32] bf16, 64B rows, chunk swizzle mask (row&3)
            #pragma unroll
            for (int rr = 0; rr < 2; ++rr) {
                int q = rr * 4 + wid;
                int off = q * 1024 + lane * 16;
                int arow = off >> 6;
                int scol = ((off >> 4) & 3) ^ (arow & 3);
                int grow = row0 + arow; if (grow >= M) grow = M - 1;
                const char* src = (const char*)A + (((size_t)grow * Kdim + k0) << 1) + scol * 16;
                GLOAD_LDS16(src, ldsA0 + buf * ABUF + q * 1024);
            }
        }
    };

    f32x4 acc[4][FN] = {};

    auto compute = [&](int buf) {
        const char* Ab = ldsA0 + buf * ABUF;
        const char* Bb = ldsB0 + buf * BBUF;
        const int kq = lane >> 4;   // k-quadrant: elements kq*8..kq*8+7
        bf16x8 af[4];
        if (af32) {
            #pragma unroll
            for (int mi = 0; mi < 4; ++mi) {
                int aRow = wrow + mi * 16 + (lane & 15);
                int base = aRow * 128 + kq * 32;
                int sw = (aRow & 7) << 4;
                f32x4 lo = *(const f32x4*)(Ab + (base ^ sw));
                f32x4 hi = *(const f32x4*)(Ab + ((base + 16) ^ sw));
                #pragma unroll
                for (int j = 0; j < 4; ++j) { af[mi][j] = (__bf16)lo[j]; af[mi][j + 4] = (__bf16)hi[j]; }
            }
        } else {
            #pragma unroll
            for (int mi = 0; mi < 4; ++mi) {
                int aRow = wrow + mi * 16 + (lane & 15);
                int o = (aRow * 64 + kq * 16) ^ ((aRow & 3) << 4);
                af[mi] = *(const bf16x8*)(Ab + o);
            }
        }
        bf16x8 bfv[FN];
        #pragma unroll
        for (int ni = 0; ni < FN; ++ni) {
            int bRow = wcol + ni * 16 + (lane & 15);
            int o = (bRow * 64 + kq * 16) ^ ((bRow & 3) << 4);
            bfv[ni] = *(const bf16x8*)(Bb + o);
        }
        #pragma unroll
        for (int mi = 0; mi < 4; ++mi)
            #pragma unroll
            for (int ni = 0; ni < FN; ++ni)
                acc[mi][ni] = __builtin_amdgcn_mfma_f32_16x16x32_bf16(af[mi], bfv[ni],
                                                                      acc[mi][ni], 0, 0, 0);
    };

    const int NT = Kdim / BK;
    stage(0, 0);
    __syncthreads();
    int buf = 0;
    for (int t = 0; t < NT; ++t) {
        if (t + 1 < NT) stage(buf ^ 1, (t + 1) * BK);   // issue next tile first
        compute(buf);                                    // ds_read + MFMA current
        __syncthreads();                                 // barrier drains vmcnt: next tile landed
        buf ^= 1;
    }

    #pragma unroll
    for (int mi = 0; mi < 4; ++mi) {
        #pragma unroll
        for (int ni = 0; ni < FN; ++ni) {
            #pragma unroll
            for (int rg = 0; rg < 4; ++rg) {
                int grow = row0 + wrow + mi * 16 + (lane >> 4) * 4 + rg;
                int gcol = col0 + wcol + ni * 16 + (lane & 15);
                if (grow < M) {
                    float vv = acc[mi][ni][rg] + bias[gcol];
                    if (RELU) vv = fmaxf(vv, 0.0f);
                    C[(size_t)grow * ldc + gcol] = f2bfu(vv);
                }
            }
        }
    }
}

// ---------------- Chebyshev propagation (round-0 verified, verbatim) ----------------
// One wave per row. lane = (sub=lane>>3 edge slot, fc=lane&7 feature chunk of 8).
// weight factored: P[r] = -dinv[r] * sum_edges dinv[c] * v[c]
// mode 0: tdst = P ; outacc = coe0/2 * vsrc[own] + coe1 * P
// mode 1: t2 = 2P - tdst[own]; tdst[own] = t2; outacc += coe[ci] * t2

__global__ __launch_bounds__(256) void prop_kernel(const unsigned short* __restrict__ vsrc,
                                                   unsigned short* __restrict__ tdst,
                                                   float* __restrict__ outacc,
                                                   const int* __restrict__ rowptr,
                                                   const int* __restrict__ cols,
                                                   const float* __restrict__ dinv,
                                                   const float* __restrict__ coe,
                                                   int mode, int ci, int n) {
    int lane = threadIdx.x & 63;
    int r = blockIdx.x * 4 + (threadIdx.x >> 6);
    if (r >= n) return;
    int fc = lane & 7;
    int sub = lane >> 3;
    int e0 = rowptr[r], e1 = rowptr[r + 1];
    float acc[8] = {};
    for (int e = e0; e < e1; e += 8) {
        int ee = e + sub;
        bool valid = ee < e1;
        int c = valid ? cols[ee] : 0;
        float w = valid ? dinv[c] : 0.0f;
        ushort8 vv = *(const ushort8*)&vsrc[(size_t)c * NOUT + fc * 8];
        #pragma unroll
        for (int j = 0; j < 8; ++j)
            acc[j] = fmaf(w, bf2f(vv[j]), acc[j]);
    }
    // reduce over sub (lanes differing in bits 3..5)
    #pragma unroll
    for (int m = 8; m < 64; m <<= 1)
        #pragma unroll
        for (int j = 0; j < 8; ++j)
            acc[j] += __shfl_xor(acc[j], m, 64);

    if (lane < 8) {   // lane w holds feats w*8 .. w*8+7 (fc==lane, sub==0)
        float dr = -dinv[r];
        size_t idx = (size_t)r * NOUT + lane * 8;
        float P[8];
        #pragma unroll
        for (int j = 0; j < 8; ++j) P[j] = dr * acc[j];
        if (mode == 0) {
            ushort8 v0 = *(const ushort8*)&vsrc[idx];
            ushort8 hout;
            #pragma unroll
            for (int j = 0; j < 8; ++j) {
                __bf16 h = (__bf16)P[j];
                hout[j] = *(unsigned short*)&h;
            }
            *(ushort8*)&tdst[idx] = hout;
            #pragma unroll
            for (int j = 0; j < 8; ++j)
                outacc[idx + j] = coe[0] * 0.5f * bf2f(v0[j]) + coe[1] * P[j];
        } else {
            ushort8 t0v = *(const ushort8*)&tdst[idx];
            ushort8 hout;
            float t2a[8];
            #pragma unroll
            for (int j = 0; j < 8; ++j) {
                float t2 = 2.0f * P[j] - bf2f(t0v[j]);
                t2a[j] = t2;
                __bf16 h = (__bf16)t2;
                hout[j] = *(unsigned short*)&h;
            }
            *(ushort8*)&tdst[idx] = hout;
            #pragma unroll
            for (int j = 0; j < 8; ++j)
                outacc[idx + j] += coe[ci] * t2a[j];
        }
    }
}

// ---------------- element-wise output convert (round-0 verified, verbatim) ----------
__global__ void convert_kernel(const float* __restrict__ in, const int* __restrict__ flag,
                               void* __restrict__ out, int n) {
    int i = blockIdx.x * blockDim.x + threadIdx.x;
    bool isbf = flag[0] != 0;
    if (i < n) {
        float v = in[i];
        if (isbf) {
            __bf16 h = (__bf16)v;
            ((unsigned short*)out)[i] = *(unsigned short*)&h;
        } else {
            ((float*)out)[i] = v;
        }
    }
}

// ---------------- launch ----------------

extern "C" void kernel_launch(void* const* d_in, const int* in_sizes, int n_in,
                              void* d_out, int out_size, void* d_ws, size_t ws_size,
                              hipStream_t stream) {
    const void* feature = d_in[0];
    const void* W1      = d_in[1];
    const void* b1      = d_in[2];
    const void* W2      = d_in[3];
    const void* b2      = d_in[4];
    const void* temp    = d_in[5];
    const int* edge_index = (const int*)d_in[6];

    const int N = in_sizes[0] / NFEAT;   // 100000
    const int E = in_sizes[6] / 2;       // 3200000
    const int* row = edge_index;
    const int* col = edge_index + E;
    const int nb = (N + SCAN_CHUNK - 1) / SCAN_CHUNK;   // 49

    char* base = (char*)d_ws;
    size_t off = 0;
    auto alloc = [&](size_t bytes) -> char* {
        char* p = base + off;
        off = (off + bytes + 255) & ~(size_t)255;
        return p;
    };
    int*   flag   = (int*)  alloc(4);
    float* coe    = (float*)alloc(64);
    int*   bsum   = (int*)  alloc(256);
    int*   boff   = (int*)  alloc(256);
    unsigned short* w1c = (unsigned short*)alloc((size_t)NHID * NFEAT * 2);
    float* b1c    = (float*)alloc(NHID * 4);
    unsigned short* w2c = (unsigned short*)alloc((size_t)NOUT * NHID * 2);
    float* b2c    = (float*)alloc(NOUT * 4);
    float* dinv   = (float*)alloc((size_t)N * 4);
    int*   deg    = (int*)  alloc((size_t)N * 4);
    int*   rowptr = (int*)  alloc((size_t)(N + 1) * 4);
    int*   cursor = (int*)  alloc((size_t)(N + 1) * 4);
    // overlay region R: xhid (N*NHID*2 = 51.2MB) lives gemm1->gemm2;
    // afterwards colss (E*4 = 12.8MB) | outacc (N*NOUT*4 = 25.6MB) live there.
    char*  R      = alloc((size_t)N * NHID * 2);
    unsigned short* xhid = (unsigned short*)R;
    int*   colss  = (int*)R;
    float* outacc = (float*)(R + (size_t)E * 4);
    unsigned short* t_a = (unsigned short*)alloc((size_t)N * NOUT * 2);
    unsigned short* t_b = (unsigned short*)alloc((size_t)N * NOUT * 2);

    // dtype flag, coefficients, canonical weights
    detect_kernel<<<1, 64, 0, stream>>>((const unsigned short*)temp, flag);
    coef_kernel<<<1, 64, 0, stream>>>(temp, flag, coe);
    prep_weights<<<128, 256, 0, stream>>>(W1, b1, W2, b2, flag, w1c, b1c, w2c, b2c);

    // dense MLP (writes xhid, then t_a = Tx0 bf16, row-major)
    const int nbm = (N + 127) / 128;
    gemm_kernel<128, 2, true, true><<<dim3(nbm * 2), 256, 0, stream>>>(
        feature, w1c, b1c, flag, xhid, N, NFEAT, NHID);
    gemm_kernel<64, 1, false, false><<<dim3(nbm), 256, 0, stream>>>(
        xhid, w2c, b2c, flag, t_a, N, NHID, NOUT);

    // graph preprocessing (xhid dead now; colss/outacc overlay it)
    hipMemsetAsync(deg, 0, (size_t)N * 4, stream);
    count_deg_kernel<<<(E + 255) / 256, 256, 0, stream>>>(row, deg, E);
    dinv_kernel<<<(N + 255) / 256, 256, 0, stream>>>(deg, dinv, N);
    partial_sum_kernel<<<nb, 256, 0, stream>>>(deg, bsum, N);
    scan_small_kernel<<<1, 64, 0, stream>>>(bsum, boff, rowptr, nb, N);
    scan_apply_kernel<<<nb, 256, 0, stream>>>(deg, boff, rowptr, cursor, N);
    scatter_kernel<<<(E + 255) / 256, 256, 0, stream>>>(row, col, cursor, colss, E);

    // Chebyshev propagation with 2 ping-pong bf16 buffers (row-major)
    int pb = (N + 3) / 4;
    prop_kernel<<<pb, 256, 0, stream>>>(t_a, t_b, outacc, rowptr, colss, dinv, coe, 0, 0, N);
    unsigned short* src = t_b;
    unsigned short* dst = t_a;
    for (int i = 2; i <= K_ORDER; ++i) {
        prop_kernel<<<pb, 256, 0, stream>>>(src, dst, outacc, rowptr, colss, dinv, coe, 1, i, N);
        unsigned short* tmp = src; src = dst; dst = tmp;
    }

    convert_kernel<<<(N * NOUT + 255) / 256, 256, 0, stream>>>(outacc, flag, d_out, N * NOUT);
}

// Round 6
// 1426.509 us; speedup vs baseline: 1.9200x; 1.0807x over previous
//
#include <hip/hip_runtime.h>

#define K_ORDER 10
#define NFEAT 512
#define NHID 256
#define NOUT 64
#define PI_F 3.14159265358979323846f
#define SCAN_CHUNK 2048

typedef __bf16 bf16x8 __attribute__((ext_vector_type(8)));
typedef unsigned short ushort8 __attribute__((ext_vector_type(8)));
typedef float f32x4 __attribute__((ext_vector_type(4)));

__device__ __forceinline__ float bf2f(unsigned short u) {
    union { unsigned int i; float f; } x;
    x.i = ((unsigned int)u) << 16;
    return x.f;
}

__device__ __forceinline__ unsigned short f2bfu(float f) {
    __bf16 h = (__bf16)f;
    return *(unsigned short*)&h;
}

#define GLOAD_LDS16(g, l) __builtin_amdgcn_global_load_lds( \
    (const __attribute__((address_space(1))) void*)(g),     \
    (__attribute__((address_space(3))) void*)(l), 16, 0, 0)

// ---------------- input dtype detection ----------------
__global__ void detect_kernel(const unsigned short* __restrict__ temp, int* __restrict__ flag) {
    if (threadIdx.x == 0 && blockIdx.x == 0) {
        int cnt = 0;
        for (int i = 0; i < K_ORDER + 1; ++i) {
            unsigned short s = temp[i];
            if (s >= 0x3E00 && s < 0x4080) cnt++;
        }
        flag[0] = (cnt >= 9) ? 1 : 0;
    }
}

// ---------------- weight canonicalization (bf16 W, f32 bias) ----------------
__global__ void prep_weights(const void* __restrict__ W1, const void* __restrict__ b1,
                             const void* __restrict__ W2, const void* __restrict__ b2,
                             const int* __restrict__ flag,
                             unsigned short* __restrict__ w1o, float* __restrict__ b1o,
                             unsigned short* __restrict__ w2o, float* __restrict__ b2o) {
    bool isbf = flag[0] != 0;
    int stride = gridDim.x * blockDim.x;
    int i0 = blockIdx.x * blockDim.x + threadIdx.x;
    const int n1 = NHID * NFEAT;
    const int n2 = NOUT * NHID;
    for (int i = i0; i < n1; i += stride)
        w1o[i] = isbf ? ((const unsigned short*)W1)[i] : f2bfu(((const float*)W1)[i]);
    for (int i = i0; i < n2; i += stride)
        w2o[i] = isbf ? ((const unsigned short*)W2)[i] : f2bfu(((const float*)W2)[i]);
    for (int i = i0; i < NHID; i += stride)
        b1o[i] = isbf ? bf2f(((const unsigned short*)b1)[i]) : ((const float*)b1)[i];
    for (int i = i0; i < NOUT; i += stride)
        b2o[i] = isbf ? bf2f(((const unsigned short*)b2)[i]) : ((const float*)b2)[i];
}

// ---------------- graph preprocessing ----------------

__global__ void count_deg_kernel(const int* __restrict__ row, int* __restrict__ deg, int e) {
    int i = blockIdx.x * blockDim.x + threadIdx.x;
    if (i < e) atomicAdd(&deg[row[i]], 1);
}

__global__ void dinv_kernel(const int* __restrict__ deg, float* __restrict__ dinv, int n) {
    int i = blockIdx.x * blockDim.x + threadIdx.x;
    if (i < n) {
        int d = deg[i];
        dinv[i] = (d > 0) ? rsqrtf((float)d) : 0.0f;
    }
}

__global__ __launch_bounds__(256) void partial_sum_kernel(const int* __restrict__ deg,
                                                          int* __restrict__ bsum, int n) {
    __shared__ int ws[4];
    int b = blockIdx.x, t = threadIdx.x;
    int base = b * SCAN_CHUNK + t * 8;
    int s = 0;
    #pragma unroll
    for (int j = 0; j < 8; ++j) { int i = base + j; if (i < n) s += deg[i]; }
    #pragma unroll
    for (int m = 1; m < 64; m <<= 1) s += __shfl_xor(s, m, 64);
    if ((t & 63) == 0) ws[t >> 6] = s;
    __syncthreads();
    if (t == 0) bsum[b] = ws[0] + ws[1] + ws[2] + ws[3];
}

// 1 block, 64 threads; nb <= 64
__global__ void scan_small_kernel(const int* __restrict__ bsum, int* __restrict__ boff,
                                  int* __restrict__ rowptr, int nb, int n) {
    int t = threadIdx.x;
    int v = (t < nb) ? bsum[t] : 0;
    int x = v;
    #pragma unroll
    for (int m = 1; m < 64; m <<= 1) { int y = __shfl_up(x, m, 64); if (t >= m) x += y; }
    if (t < nb) boff[t] = x - v;
    if (t == 63) rowptr[n] = x;
}

__global__ __launch_bounds__(256) void scan_apply_kernel(const int* __restrict__ deg,
                                                         const int* __restrict__ boff,
                                                         int* __restrict__ rowptr,
                                                         int* __restrict__ cursor, int n) {
    __shared__ int wtot[4];
    __shared__ int woff_s[4];
    int b = blockIdx.x, t = threadIdx.x;
    int lane = t & 63, wid = t >> 6;
    int base = b * SCAN_CHUNK + t * 8;
    int v[8], s[8];
    int run = 0;
    #pragma unroll
    for (int j = 0; j < 8; ++j) {
        int i = base + j;
        v[j] = (i < n) ? deg[i] : 0;
        run += v[j];
        s[j] = run;
    }
    int tsum = run;
    int x = tsum;
    #pragma unroll
    for (int m = 1; m < 64; m <<= 1) { int y = __shfl_up(x, m, 64); if (lane >= m) x += y; }
    int texcl = x - tsum;
    if (lane == 63) wtot[wid] = x;
    __syncthreads();
    if (t == 0) {
        int r = 0;
        #pragma unroll
        for (int w = 0; w < 4; ++w) { woff_s[w] = r; r += wtot[w]; }
    }
    __syncthreads();
    int ebase = boff[b] + woff_s[wid] + texcl;
    #pragma unroll
    for (int j = 0; j < 8; ++j) {
        int i = base + j;
        if (i < n) { int ex = ebase + s[j] - v[j]; rowptr[i] = ex; cursor[i] = ex; }
    }
}

// ---- partition bounds: split row space into 8 equal-edge ranges via rowptr ----
__global__ void part_bounds_kernel(const int* __restrict__ rowptr, int* __restrict__ pb,
                                   int n, int e) {
    int j = threadIdx.x;
    if (j > 8) return;
    if (j == 8) { pb[8] = n; return; }
    long target = (long)j * e / 8;
    int lo = 0, hi = n;
    while (lo < hi) {
        int mid = (lo + hi) >> 1;
        if ((long)rowptr[mid] < target) lo = mid + 1; else hi = mid;
    }
    pb[j] = lo;
}

// ---- XCD-partitioned scatter: single pass, write-locality via row-range partition.
// Partition j (rows pb[j]..pb[j+1]) is handled ONLY by blocks with bid%8==j, which
// round-robin dispatch places on XCD j -> that partition's 1.6MB cols_s region and
// its cursor lines stay resident in XCD j's 4MB L2, so the ~16 scattered 4B writes
// per 64B line combine in L2 instead of each evicting a nearly-empty dirty line
// (old WRITE_SIZE 194MB for a 12.8MB payload). The 8x edge-list re-read is served
// by L3 (row/col = 25.6MB, L3-resident after count_deg). Mapping is a perf-only
// heuristic: wrong mapping degrades locality, never correctness.
__global__ __launch_bounds__(256) void scatter_part_kernel(
    const int* __restrict__ row, const int* __restrict__ col,
    const int* __restrict__ pbounds, int* __restrict__ cursor,
    int* __restrict__ cols_s, int e) {
    const int j = blockIdx.x & 7;
    const int lo = pbounds[j], hi = pbounds[j + 1];
    const int base = ((blockIdx.x >> 3) * 256 + threadIdx.x) * 4;
    if (base + 3 < e) {
        int4 r4 = *(const int4*)(row + base);
        int4 c4 = *(const int4*)(col + base);
        #pragma unroll
        for (int k = 0; k < 4; ++k) {
            int r = (&r4.x)[k];
            if (r >= lo && r < hi) {
                int p = atomicAdd(&cursor[r], 1);
                cols_s[p] = (&c4.x)[k];
            }
        }
    } else {
        for (int k = 0; k < 4; ++k) {
            int i = base + k;
            if (i < e) {
                int r = row[i];
                if (r >= lo && r < hi) {
                    int p = atomicAdd(&cursor[r], 1);
                    cols_s[p] = col[i];
                }
            }
        }
    }
}

// ---------------- Chebyshev coefficients ----------------

__global__ void coef_kernel(const void* __restrict__ temp, const int* __restrict__ flag,
                            float* __restrict__ coe) {
    int i = threadIdx.x;
    bool isbf = flag[0] != 0;
    if (i <= K_ORDER) {
        float s = 0.0f;
        #pragma unroll
        for (int j = 0; j <= K_ORDER; ++j) {
            float t = isbf ? bf2f(((const unsigned short*)temp)[j]) : ((const float*)temp)[j];
            t = fmaxf(t, 0.0f);
            float theta = ((float)(K_ORDER - j) + 0.5f) * PI_F / (float)(K_ORDER + 1);
            s += cosf((float)i * theta) * t;
        }
        coe[i] = (2.0f / (float)(K_ORDER + 1)) * s;
    }
}

// ---------------- MFMA GEMM: global_load_lds staging + 2-phase pipeline ----------------
// A: runtime f32-or-bf16 when A_FLAGGED; B: canonical bf16; bias: canonical f32.
// Swizzle (rule #21, both-sides involution): linear LDS dest (HW requirement),
// inverse-swizzled per-lane GLOBAL source, same XOR applied on ds_read.
// One __syncthreads per K-step; next tile's loads issued before current compute.

template<int BN, int NBY, bool RELU, bool A_FLAGGED>
__global__ __launch_bounds__(256) void gemm_kernel(
    const void* __restrict__ A, const unsigned short* __restrict__ Bw,
    const float* __restrict__ bias, const int* __restrict__ flag,
    unsigned short* __restrict__ C, int M, int Kdim, int ldc)
{
    constexpr int BM = 128, BK = 32;
    constexpr int FN = BN / 32;
    constexpr int ABUF = A_FLAGGED ? (BM * BK * 4) : (BM * BK * 2);
    constexpr int BBUF = BN * BK * 2;
    __shared__ char lds[2 * ABUF + 2 * BBUF] __attribute__((aligned(16)));

    const int tid = threadIdx.x;
    const int lane = tid & 63, wid = tid >> 6;
    const int bid = blockIdx.x;
    const int by = bid % NBY;        // col-blocks dispatch-adjacent for A reuse
    const int bx = bid / NBY;
    const int row0 = bx * BM;
    const int col0 = by * BN;
    const int wrow = (wid >> 1) * (BM / 2);
    const int wcol = (wid & 1) * (BN / 2);
    const bool af32 = A_FLAGGED ? (flag[0] == 0) : false;

    char* ldsA0 = lds;
    char* ldsB0 = lds + 2 * ABUF;

    auto stage = [&](int buf, int k0) {
        {   // B tile [BN][BK] bf16, 64B rows, chunk swizzle mask (row&3)
            constexpr int PW = (BBUF / 1024) / 4;   // 2 (BN=128) or 1 (BN=64)
            #pragma unroll
            for (int rr = 0; rr < PW; ++rr) {
                int q = rr * 4 + wid;
                int off = q * 1024 + lane * 16;
                int brow = off >> 6;
                int scol = ((off >> 4) & 3) ^ (brow & 3);
                const char* src = (const char*)Bw + (((size_t)(col0 + brow) * Kdim + k0) << 1) + scol * 16;
                GLOAD_LDS16(src, ldsB0 + buf * BBUF + q * 1024);
            }
        }
        if (af32) {         // A tile [128][32] f32, 128B rows, chunk swizzle mask (row&7)
            #pragma unroll
            for (int rr = 0; rr < 4; ++rr) {
                int q = rr * 4 + wid;
                int off = q * 1024 + lane * 16;
                int arow = off >> 7;
                int scol = ((off >> 4) & 7) ^ (arow & 7);
                int grow = row0 + arow; if (grow >= M) grow = M - 1;
                const char* src = (const char*)A + (((size_t)grow * Kdim + k0) << 2) + scol * 16;
                GLOAD_LDS16(src, ldsA0 + buf * ABUF + q * 1024);
            }
        } else {            // A tile [128][32] bf16, 64B rows, chunk swizzle mask (row&3)
            #pragma unroll
            for (int rr = 0; rr < 2; ++rr) {
                int q = rr * 4 + wid;
                int off = q * 1024 + lane * 16;
                int arow = off >> 6;
                int scol = ((off >> 4) & 3) ^ (arow & 3);
                int grow = row0 + arow; if (grow >= M) grow = M - 1;
                const char* src = (const char*)A + (((size_t)grow * Kdim + k0) << 1) + scol * 16;
                GLOAD_LDS16(src, ldsA0 + buf * ABUF + q * 1024);
            }
        }
    };

    f32x4 acc[4][FN] = {};

    auto compute = [&](int buf) {
        const char* Ab = ldsA0 + buf * ABUF;
        const char* Bb = ldsB0 + buf * BBUF;
        const int kq = lane >> 4;   // k-quadrant: elements kq*8..kq*8+7
        bf16x8 af[4];
        if (af32) {
            #pragma unroll
            for (int mi = 0; mi < 4; ++mi) {
                int aRow = wrow + mi * 16 + (lane & 15);
                int base = aRow * 128 + kq * 32;
                int sw = (aRow & 7) << 4;
                f32x4 lo = *(const f32x4*)(Ab + (base ^ sw));
                f32x4 hi = *(const f32x4*)(Ab + ((base + 16) ^ sw));
                #pragma unroll
                for (int j = 0; j < 4; ++j) { af[mi][j] = (__bf16)lo[j]; af[mi][j + 4] = (__bf16)hi[j]; }
            }
        } else {
            #pragma unroll
            for (int mi = 0; mi < 4; ++mi) {
                int aRow = wrow + mi * 16 + (lane & 15);
                int o = (aRow * 64 + kq * 16) ^ ((aRow & 3) << 4);
                af[mi] = *(const bf16x8*)(Ab + o);
            }
        }
        bf16x8 bfv[FN];
        #pragma unroll
        for (int ni = 0; ni < FN; ++ni) {
            int bRow = wcol + ni * 16 + (lane & 15);
            int o = (bRow * 64 + kq * 16) ^ ((bRow & 3) << 4);
            bfv[ni] = *(const bf16x8*)(Bb + o);
        }
        #pragma unroll
        for (int mi = 0; mi < 4; ++mi)
            #pragma unroll
            for (int ni = 0; ni < FN; ++ni)
                acc[mi][ni] = __builtin_amdgcn_mfma_f32_16x16x32_bf16(af[mi], bfv[ni],
                                                                      acc[mi][ni], 0, 0, 0);
    };

    const int NT = Kdim / BK;
    stage(0, 0);
    __syncthreads();
    int buf = 0;
    for (int t = 0; t < NT; ++t) {
        if (t + 1 < NT) stage(buf ^ 1, (t + 1) * BK);   // issue next tile first
        compute(buf);                                    // ds_read + MFMA current
        __syncthreads();                                 // barrier drains vmcnt: next tile landed
        buf ^= 1;
    }

    #pragma unroll
    for (int mi = 0; mi < 4; ++mi) {
        #pragma unroll
        for (int ni = 0; ni < FN; ++ni) {
            #pragma unroll
            for (int rg = 0; rg < 4; ++rg) {
                int grow = row0 + wrow + mi * 16 + (lane >> 4) * 4 + rg;
                int gcol = col0 + wcol + ni * 16 + (lane & 15);
                if (grow < M) {
                    float vv = acc[mi][ni][rg] + bias[gcol];
                    if (RELU) vv = fmaxf(vv, 0.0f);
                    C[(size_t)grow * ldc + gcol] = f2bfu(vv);
                }
            }
        }
    }
}

// ---------------- Chebyshev propagation (round-0 verified, verbatim) ----------------
// One wave per row. lane = (sub=lane>>3 edge slot, fc=lane&7 feature chunk of 8).
// weight factored: P[r] = -dinv[r] * sum_edges dinv[c] * v[c]
// mode 0: tdst = P ; outacc = coe0/2 * vsrc[own] + coe1 * P
// mode 1: t2 = 2P - tdst[own]; tdst[own] = t2; outacc += coe[ci] * t2

__global__ __launch_bounds__(256) void prop_kernel(const unsigned short* __restrict__ vsrc,
                                                   unsigned short* __restrict__ tdst,
                                                   float* __restrict__ outacc,
                                                   const int* __restrict__ rowptr,
                                                   const int* __restrict__ cols,
                                                   const float* __restrict__ dinv,
                                                   const float* __restrict__ coe,
                                                   int mode, int ci, int n) {
    int lane = threadIdx.x & 63;
    int r = blockIdx.x * 4 + (threadIdx.x >> 6);
    if (r >= n) return;
    int fc = lane & 7;
    int sub = lane >> 3;
    int e0 = rowptr[r], e1 = rowptr[r + 1];
    float acc[8] = {};
    for (int e = e0; e < e1; e += 8) {
        int ee = e + sub;
        bool valid = ee < e1;
        int c = valid ? cols[ee] : 0;
        float w = valid ? dinv[c] : 0.0f;
        ushort8 vv = *(const ushort8*)&vsrc[(size_t)c * NOUT + fc * 8];
        #pragma unroll
        for (int j = 0; j < 8; ++j)
            acc[j] = fmaf(w, bf2f(vv[j]), acc[j]);
    }
    // reduce over sub (lanes differing in bits 3..5)
    #pragma unroll
    for (int m = 8; m < 64; m <<= 1)
        #pragma unroll
        for (int j = 0; j < 8; ++j)
            acc[j] += __shfl_xor(acc[j], m, 64);

    if (lane < 8) {   // lane w holds feats w*8 .. w*8+7 (fc==lane, sub==0)
        float dr = -dinv[r];
        size_t idx = (size_t)r * NOUT + lane * 8;
        float P[8];
        #pragma unroll
        for (int j = 0; j < 8; ++j) P[j] = dr * acc[j];
        if (mode == 0) {
            ushort8 v0 = *(const ushort8*)&vsrc[idx];
            ushort8 hout;
            #pragma unroll
            for (int j = 0; j < 8; ++j) {
                __bf16 h = (__bf16)P[j];
                hout[j] = *(unsigned short*)&h;
            }
            *(ushort8*)&tdst[idx] = hout;
            #pragma unroll
            for (int j = 0; j < 8; ++j)
                outacc[idx + j] = coe[0] * 0.5f * bf2f(v0[j]) + coe[1] * P[j];
        } else {
            ushort8 t0v = *(const ushort8*)&tdst[idx];
            ushort8 hout;
            float t2a[8];
            #pragma unroll
            for (int j = 0; j < 8; ++j) {
                float t2 = 2.0f * P[j] - bf2f(t0v[j]);
                t2a[j] = t2;
                __bf16 h = (__bf16)t2;
                hout[j] = *(unsigned short*)&h;
            }
            *(ushort8*)&tdst[idx] = hout;
            #pragma unroll
            for (int j = 0; j < 8; ++j)
                outacc[idx + j] += coe[ci] * t2a[j];
        }
    }
}

// ---------------- element-wise output convert (round-0 verified, verbatim) ----------
__global__ void convert_kernel(const float* __restrict__ in, const int* __restrict__ flag,
                               void* __restrict__ out, int n) {
    int i = blockIdx.x * blockDim.x + threadIdx.x;
    bool isbf = flag[0] != 0;
    if (i < n) {
        float v = in[i];
        if (isbf) {
            __bf16 h = (__bf16)v;
            ((unsigned short*)out)[i] = *(unsigned short*)&h;
        } else {
            ((float*)out)[i] = v;
        }
    }
}

// ---------------- launch ----------------

extern "C" void kernel_launch(void* const* d_in, const int* in_sizes, int n_in,
                              void* d_out, int out_size, void* d_ws, size_t ws_size,
                              hipStream_t stream) {
    const void* feature = d_in[0];
    const void* W1      = d_in[1];
    const void* b1      = d_in[2];
    const void* W2      = d_in[3];
    const void* b2      = d_in[4];
    const void* temp    = d_in[5];
    const int* edge_index = (const int*)d_in[6];

    const int N = in_sizes[0] / NFEAT;   // 100000
    const int E = in_sizes[6] / 2;       // 3200000
    const int* row = edge_index;
    const int* col = edge_index + E;
    const int nb = (N + SCAN_CHUNK - 1) / SCAN_CHUNK;   // 49

    char* base = (char*)d_ws;
    size_t off = 0;
    auto alloc = [&](size_t bytes) -> char* {
        char* p = base + off;
        off = (off + bytes + 255) & ~(size_t)255;
        return p;
    };
    int*   flag   = (int*)  alloc(4);
    float* coe    = (float*)alloc(64);
    int*   bsum   = (int*)  alloc(256);
    int*   boff   = (int*)  alloc(256);
    int*   pbounds= (int*)  alloc(64);
    unsigned short* w1c = (unsigned short*)alloc((size_t)NHID * NFEAT * 2);
    float* b1c    = (float*)alloc(NHID * 4);
    unsigned short* w2c = (unsigned short*)alloc((size_t)NOUT * NHID * 2);
    float* b2c    = (float*)alloc(NOUT * 4);
    float* dinv   = (float*)alloc((size_t)N * 4);
    int*   deg    = (int*)  alloc((size_t)N * 4);
    int*   rowptr = (int*)  alloc((size_t)(N + 1) * 4);
    int*   cursor = (int*)  alloc((size_t)(N + 1) * 4);
    // overlay region R: xhid (N*NHID*2 = 51.2MB) lives gemm1->gemm2;
    // afterwards colss (E*4 = 12.8MB) | outacc (N*NOUT*4 = 25.6MB) live there.
    char*  R      = alloc((size_t)N * NHID * 2);
    unsigned short* xhid = (unsigned short*)R;
    int*   colss  = (int*)R;
    float* outacc = (float*)(R + (size_t)E * 4);
    unsigned short* t_a = (unsigned short*)alloc((size_t)N * NOUT * 2);
    unsigned short* t_b = (unsigned short*)alloc((size_t)N * NOUT * 2);

    // dtype flag, coefficients, canonical weights
    detect_kernel<<<1, 64, 0, stream>>>((const unsigned short*)temp, flag);
    coef_kernel<<<1, 64, 0, stream>>>(temp, flag, coe);
    prep_weights<<<128, 256, 0, stream>>>(W1, b1, W2, b2, flag, w1c, b1c, w2c, b2c);

    // dense MLP (writes xhid, then t_a = Tx0 bf16, row-major)
    const int nbm = (N + 127) / 128;
    gemm_kernel<128, 2, true, true><<<dim3(nbm * 2), 256, 0, stream>>>(
        feature, w1c, b1c, flag, xhid, N, NFEAT, NHID);
    gemm_kernel<64, 1, false, false><<<dim3(nbm), 256, 0, stream>>>(
        xhid, w2c, b2c, flag, t_a, N, NHID, NOUT);

    // graph preprocessing (xhid dead now; colss/outacc overlay it)
    hipMemsetAsync(deg, 0, (size_t)N * 4, stream);
    count_deg_kernel<<<(E + 255) / 256, 256, 0, stream>>>(row, deg, E);
    dinv_kernel<<<(N + 255) / 256, 256, 0, stream>>>(deg, dinv, N);
    partial_sum_kernel<<<nb, 256, 0, stream>>>(deg, bsum, N);
    scan_small_kernel<<<1, 64, 0, stream>>>(bsum, boff, rowptr, nb, N);
    scan_apply_kernel<<<nb, 256, 0, stream>>>(deg, boff, rowptr, cursor, N);
    // XCD-partitioned scatter (replaces the random 4B-store scatter)
    part_bounds_kernel<<<1, 16, 0, stream>>>(rowptr, pbounds, N, E);
    {
        int nch = (E + 1023) / 1024;   // 4 edges/thread
        scatter_part_kernel<<<nch * 8, 256, 0, stream>>>(row, col, pbounds, cursor, colss, E);
    }

    // Chebyshev propagation with 2 ping-pong bf16 buffers (row-major)
    int pb = (N + 3) / 4;
    prop_kernel<<<pb, 256, 0, stream>>>(t_a, t_b, outacc, rowptr, colss, dinv, coe, 0, 0, N);
    unsigned short* src = t_b;
    unsigned short* dst = t_a;
    for (int i = 2; i <= K_ORDER; ++i) {
        prop_kernel<<<pb, 256, 0, stream>>>(src, dst, outacc, rowptr, colss, dinv, coe, 1, i, N);
        unsigned short* tmp = src; src = dst; dst = tmp;
    }

    convert_kernel<<<(N * NOUT + 255) / 256, 256, 0, stream>>>(outacc, flag, d_out, N * NOUT);
}

// Round 7
// 1386.016 us; speedup vs baseline: 1.9761x; 1.0292x over previous
//
#include <hip/hip_runtime.h>

#define K_ORDER 10
#define NFEAT 512
#define NHID 256
#define NOUT 64
#define PI_F 3.14159265358979323846f
#define SCAN_CHUNK 2048

typedef __bf16 bf16x8 __attribute__((ext_vector_type(8)));
typedef unsigned short ushort8 __attribute__((ext_vector_type(8)));
typedef float f32x4 __attribute__((ext_vector_type(4)));

__device__ __forceinline__ float bf2f(unsigned short u) {
    union { unsigned int i; float f; } x;
    x.i = ((unsigned int)u) << 16;
    return x.f;
}

__device__ __forceinline__ unsigned short f2bfu(float f) {
    __bf16 h = (__bf16)f;
    return *(unsigned short*)&h;
}

#define GLOAD_LDS16(g, l) __builtin_amdgcn_global_load_lds( \
    (const __attribute__((address_space(1))) void*)(g),     \
    (__attribute__((address_space(3))) void*)(l), 16, 0, 0)

// ---------------- input dtype detection ----------------
__global__ void detect_kernel(const unsigned short* __restrict__ temp, int* __restrict__ flag) {
    if (threadIdx.x == 0 && blockIdx.x == 0) {
        int cnt = 0;
        for (int i = 0; i < K_ORDER + 1; ++i) {
            unsigned short s = temp[i];
            if (s >= 0x3E00 && s < 0x4080) cnt++;
        }
        flag[0] = (cnt >= 9) ? 1 : 0;
    }
}

// ---------------- weight canonicalization (bf16 W, f32 bias) ----------------
__global__ void prep_weights(const void* __restrict__ W1, const void* __restrict__ b1,
                             const void* __restrict__ W2, const void* __restrict__ b2,
                             const int* __restrict__ flag,
                             unsigned short* __restrict__ w1o, float* __restrict__ b1o,
                             unsigned short* __restrict__ w2o, float* __restrict__ b2o) {
    bool isbf = flag[0] != 0;
    int stride = gridDim.x * blockDim.x;
    int i0 = blockIdx.x * blockDim.x + threadIdx.x;
    const int n1 = NHID * NFEAT;
    const int n2 = NOUT * NHID;
    for (int i = i0; i < n1; i += stride)
        w1o[i] = isbf ? ((const unsigned short*)W1)[i] : f2bfu(((const float*)W1)[i]);
    for (int i = i0; i < n2; i += stride)
        w2o[i] = isbf ? ((const unsigned short*)W2)[i] : f2bfu(((const float*)W2)[i]);
    for (int i = i0; i < NHID; i += stride)
        b1o[i] = isbf ? bf2f(((const unsigned short*)b1)[i]) : ((const float*)b1)[i];
    for (int i = i0; i < NOUT; i += stride)
        b2o[i] = isbf ? bf2f(((const unsigned short*)b2)[i]) : ((const float*)b2)[i];
}

// ---------------- graph preprocessing ----------------

__global__ void count_deg_kernel(const int* __restrict__ row, int* __restrict__ deg, int e) {
    int i = blockIdx.x * blockDim.x + threadIdx.x;
    if (i < e) atomicAdd(&deg[row[i]], 1);
}

__global__ void dinv_kernel(const int* __restrict__ deg, float* __restrict__ dinv, int n) {
    int i = blockIdx.x * blockDim.x + threadIdx.x;
    if (i < n) {
        int d = deg[i];
        dinv[i] = (d > 0) ? rsqrtf((float)d) : 0.0f;
    }
}

__global__ __launch_bounds__(256) void partial_sum_kernel(const int* __restrict__ deg,
                                                          int* __restrict__ bsum, int n) {
    __shared__ int ws[4];
    int b = blockIdx.x, t = threadIdx.x;
    int base = b * SCAN_CHUNK + t * 8;
    int s = 0;
    #pragma unroll
    for (int j = 0; j < 8; ++j) { int i = base + j; if (i < n) s += deg[i]; }
    #pragma unroll
    for (int m = 1; m < 64; m <<= 1) s += __shfl_xor(s, m, 64);
    if ((t & 63) == 0) ws[t >> 6] = s;
    __syncthreads();
    if (t == 0) bsum[b] = ws[0] + ws[1] + ws[2] + ws[3];
}

// 1 block, 64 threads; nb <= 64
__global__ void scan_small_kernel(const int* __restrict__ bsum, int* __restrict__ boff,
                                  int* __restrict__ rowptr, int nb, int n) {
    int t = threadIdx.x;
    int v = (t < nb) ? bsum[t] : 0;
    int x = v;
    #pragma unroll
    for (int m = 1; m < 64; m <<= 1) { int y = __shfl_up(x, m, 64); if (t >= m) x += y; }
    if (t < nb) boff[t] = x - v;
    if (t == 63) rowptr[n] = x;
}

__global__ __launch_bounds__(256) void scan_apply_kernel(const int* __restrict__ deg,
                                                         const int* __restrict__ boff,
                                                         int* __restrict__ rowptr,
                                                         int* __restrict__ cursor, int n) {
    __shared__ int wtot[4];
    __shared__ int woff_s[4];
    int b = blockIdx.x, t = threadIdx.x;
    int lane = t & 63, wid = t >> 6;
    int base = b * SCAN_CHUNK + t * 8;
    int v[8], s[8];
    int run = 0;
    #pragma unroll
    for (int j = 0; j < 8; ++j) {
        int i = base + j;
        v[j] = (i < n) ? deg[i] : 0;
        run += v[j];
        s[j] = run;
    }
    int tsum = run;
    int x = tsum;
    #pragma unroll
    for (int m = 1; m < 64; m <<= 1) { int y = __shfl_up(x, m, 64); if (lane >= m) x += y; }
    int texcl = x - tsum;
    if (lane == 63) wtot[wid] = x;
    __syncthreads();
    if (t == 0) {
        int r = 0;
        #pragma unroll
        for (int w = 0; w < 4; ++w) { woff_s[w] = r; r += wtot[w]; }
    }
    __syncthreads();
    int ebase = boff[b] + woff_s[wid] + texcl;
    #pragma unroll
    for (int j = 0; j < 8; ++j) {
        int i = base + j;
        if (i < n) { int ex = ebase + s[j] - v[j]; rowptr[i] = ex; cursor[i] = ex; }
    }
}

// ---- partition bounds: split row space into 8 equal-edge ranges via rowptr ----
__global__ void part_bounds_kernel(const int* __restrict__ rowptr, int* __restrict__ pb,
                                   int n, int e) {
    int j = threadIdx.x;
    if (j > 8) return;
    if (j == 8) { pb[8] = n; return; }
    long target = (long)j * e / 8;
    int lo = 0, hi = n;
    while (lo < hi) {
        int mid = (lo + hi) >> 1;
        if ((long)rowptr[mid] < target) lo = mid + 1; else hi = mid;
    }
    pb[j] = lo;
}

// ---- XCD-partitioned scatter (round-6 verified: 136us vs 276 baseline) ----
__global__ __launch_bounds__(256) void scatter_part_kernel(
    const int* __restrict__ row, const int* __restrict__ col,
    const int* __restrict__ pbounds, int* __restrict__ cursor,
    int* __restrict__ cols_s, int e) {
    const int j = blockIdx.x & 7;
    const int lo = pbounds[j], hi = pbounds[j + 1];
    const int base = ((blockIdx.x >> 3) * 256 + threadIdx.x) * 4;
    if (base + 3 < e) {
        int4 r4 = *(const int4*)(row + base);
        int4 c4 = *(const int4*)(col + base);
        #pragma unroll
        for (int k = 0; k < 4; ++k) {
            int r = (&r4.x)[k];
            if (r >= lo && r < hi) {
                int p = atomicAdd(&cursor[r], 1);
                cols_s[p] = (&c4.x)[k];
            }
        }
    } else {
        for (int k = 0; k < 4; ++k) {
            int i = base + k;
            if (i < e) {
                int r = row[i];
                if (r >= lo && r < hi) {
                    int p = atomicAdd(&cursor[r], 1);
                    cols_s[p] = col[i];
                }
            }
        }
    }
}

// ---- per-slot edge weights: wn[p] = dinv[cols_s[p]] (removes the middle hop of
// prop's cols->dinv->vsrc dependent-load chain; dinv is a 400KB L2-hot table) ----
__global__ void wnorm_kernel(const int* __restrict__ cols_s, const float* __restrict__ dinv,
                             float* __restrict__ wn, int e) {
    int base = (blockIdx.x * blockDim.x + threadIdx.x) * 4;
    if (base + 3 < e) {
        int4 c4 = *(const int4*)(cols_s + base);
        f32x4 w4;
        w4[0] = dinv[c4.x]; w4[1] = dinv[c4.y]; w4[2] = dinv[c4.z]; w4[3] = dinv[c4.w];
        *(f32x4*)(wn + base) = w4;
    } else {
        for (int k = 0; k < 4; ++k) {
            int i = base + k;
            if (i < e) wn[i] = dinv[cols_s[i]];
        }
    }
}

// ---------------- Chebyshev coefficients ----------------

__global__ void coef_kernel(const void* __restrict__ temp, const int* __restrict__ flag,
                            float* __restrict__ coe) {
    int i = threadIdx.x;
    bool isbf = flag[0] != 0;
    if (i <= K_ORDER) {
        float s = 0.0f;
        #pragma unroll
        for (int j = 0; j <= K_ORDER; ++j) {
            float t = isbf ? bf2f(((const unsigned short*)temp)[j]) : ((const float*)temp)[j];
            t = fmaxf(t, 0.0f);
            float theta = ((float)(K_ORDER - j) + 0.5f) * PI_F / (float)(K_ORDER + 1);
            s += cosf((float)i * theta) * t;
        }
        coe[i] = (2.0f / (float)(K_ORDER + 1)) * s;
    }
}

// ---------------- MFMA GEMM: global_load_lds staging + 2-phase pipeline ----------------

template<int BN, int NBY, bool RELU, bool A_FLAGGED>
__global__ __launch_bounds__(256) void gemm_kernel(
    const void* __restrict__ A, const unsigned short* __restrict__ Bw,
    const float* __restrict__ bias, const int* __restrict__ flag,
    unsigned short* __restrict__ C, int M, int Kdim, int ldc)
{
    constexpr int BM = 128, BK = 32;
    constexpr int FN = BN / 32;
    constexpr int ABUF = A_FLAGGED ? (BM * BK * 4) : (BM * BK * 2);
    constexpr int BBUF = BN * BK * 2;
    __shared__ char lds[2 * ABUF + 2 * BBUF] __attribute__((aligned(16)));

    const int tid = threadIdx.x;
    const int lane = tid & 63, wid = tid >> 6;
    const int bid = blockIdx.x;
    const int by = bid % NBY;
    const int bx = bid / NBY;
    const int row0 = bx * BM;
    const int col0 = by * BN;
    const int wrow = (wid >> 1) * (BM / 2);
    const int wcol = (wid & 1) * (BN / 2);
    const bool af32 = A_FLAGGED ? (flag[0] == 0) : false;

    char* ldsA0 = lds;
    char* ldsB0 = lds + 2 * ABUF;

    auto stage = [&](int buf, int k0) {
        {
            constexpr int PW = (BBUF / 1024) / 4;
            #pragma unroll
            for (int rr = 0; rr < PW; ++rr) {
                int q = rr * 4 + wid;
                int off = q * 1024 + lane * 16;
                int brow = off >> 6;
                int scol = ((off >> 4) & 3) ^ (brow & 3);
                const char* src = (const char*)Bw + (((size_t)(col0 + brow) * Kdim + k0) << 1) + scol * 16;
                GLOAD_LDS16(src, ldsB0 + buf * BBUF + q * 1024);
            }
        }
        if (af32) {
            #pragma unroll
            for (int rr = 0; rr < 4; ++rr) {
                int q = rr * 4 + wid;
                int off = q * 1024 + lane * 16;
                int arow = off >> 7;
                int scol = ((off >> 4) & 7) ^ (arow & 7);
                int grow = row0 + arow; if (grow >= M) grow = M - 1;
                const char* src = (const char*)A + (((size_t)grow * Kdim + k0) << 2) + scol * 16;
                GLOAD_LDS16(src, ldsA0 + buf * ABUF + q * 1024);
            }
        } else {
            #pragma unroll
            for (int rr = 0; rr < 2; ++rr) {
                int q = rr * 4 + wid;
                int off = q * 1024 + lane * 16;
                int arow = off >> 6;
                int scol = ((off >> 4) & 3) ^ (arow & 3);
                int grow = row0 + arow; if (grow >= M) grow = M - 1;
                const char* src = (const char*)A + (((size_t)grow * Kdim + k0) << 1) + scol * 16;
                GLOAD_LDS16(src, ldsA0 + buf * ABUF + q * 1024);
            }
        }
    };

    f32x4 acc[4][FN] = {};

    auto compute = [&](int buf) {
        const char* Ab = ldsA0 + buf * ABUF;
        const char* Bb = ldsB0 + buf * BBUF;
        const int kq = lane >> 4;
        bf16x8 af[4];
        if (af32) {
            #pragma unroll
            for (int mi = 0; mi < 4; ++mi) {
                int aRow = wrow + mi * 16 + (lane & 15);
                int base = aRow * 128 + kq * 32;
                int sw = (aRow & 7) << 4;
                f32x4 lo = *(const f32x4*)(Ab + (base ^ sw));
                f32x4 hi = *(const f32x4*)(Ab + ((base + 16) ^ sw));
                #pragma unroll
                for (int j = 0; j < 4; ++j) { af[mi][j] = (__bf16)lo[j]; af[mi][j + 4] = (__bf16)hi[j]; }
            }
        } else {
            #pragma unroll
            for (int mi = 0; mi < 4; ++mi) {
                int aRow = wrow + mi * 16 + (lane & 15);
                int o = (aRow * 64 + kq * 16) ^ ((aRow & 3) << 4);
                af[mi] = *(const bf16x8*)(Ab + o);
            }
        }
        bf16x8 bfv[FN];
        #pragma unroll
        for (int ni = 0; ni < FN; ++ni) {
            int bRow = wcol + ni * 16 + (lane & 15);
            int o = (bRow * 64 + kq * 16) ^ ((bRow & 3) << 4);
            bfv[ni] = *(const bf16x8*)(Bb + o);
        }
        #pragma unroll
        for (int mi = 0; mi < 4; ++mi)
            #pragma unroll
            for (int ni = 0; ni < FN; ++ni)
                acc[mi][ni] = __builtin_amdgcn_mfma_f32_16x16x32_bf16(af[mi], bfv[ni],
                                                                      acc[mi][ni], 0, 0, 0);
    };

    const int NT = Kdim / BK;
    stage(0, 0);
    __syncthreads();
    int buf = 0;
    for (int t = 0; t < NT; ++t) {
        if (t + 1 < NT) stage(buf ^ 1, (t + 1) * BK);
        compute(buf);
        __syncthreads();
        buf ^= 1;
    }

    #pragma unroll
    for (int mi = 0; mi < 4; ++mi) {
        #pragma unroll
        for (int ni = 0; ni < FN; ++ni) {
            #pragma unroll
            for (int rg = 0; rg < 4; ++rg) {
                int grow = row0 + wrow + mi * 16 + (lane >> 4) * 4 + rg;
                int gcol = col0 + wcol + ni * 16 + (lane & 15);
                if (grow < M) {
                    float vv = acc[mi][ni][rg] + bias[gcol];
                    if (RELU) vv = fmaxf(vv, 0.0f);
                    C[(size_t)grow * ldc + gcol] = f2bfu(vv);
                }
            }
        }
    }
}

// ---------------- Chebyshev propagation ----------------
// Round-0 structure (wave per row, sub=lane>>3 edge slot, fc=lane&7 feat chunk),
// latency-optimized: (1) wn[] replaces the dependent dinv[c] gather (chain now
// cols->vsrc, 2-deep); (2) edge loop unrolled 4x -> 4 independent gather batches
// (4KB) in flight per wave instead of 1. Epilogue verbatim from round 0.

__global__ __launch_bounds__(256) void prop_kernel(const unsigned short* __restrict__ vsrc,
                                                   unsigned short* __restrict__ tdst,
                                                   float* __restrict__ outacc,
                                                   const int* __restrict__ rowptr,
                                                   const int* __restrict__ cols,
                                                   const float* __restrict__ wn,
                                                   const float* __restrict__ dinv,
                                                   const float* __restrict__ coe,
                                                   int mode, int ci, int n) {
    int lane = threadIdx.x & 63;
    int r = blockIdx.x * 4 + (threadIdx.x >> 6);
    if (r >= n) return;
    int fc = lane & 7;
    int sub = lane >> 3;
    int e0 = rowptr[r], e1 = rowptr[r + 1];
    float acc[8] = {};
    for (int e = e0; e < e1; e += 32) {
        int cc[4]; float ww[4];
        #pragma unroll
        for (int u = 0; u < 4; ++u) {
            int ee = e + u * 8 + sub;
            bool valid = ee < e1;
            cc[u] = valid ? cols[ee] : 0;
            ww[u] = valid ? wn[ee] : 0.0f;
        }
        #pragma unroll
        for (int u = 0; u < 4; ++u) {
            ushort8 vv = *(const ushort8*)&vsrc[(size_t)cc[u] * NOUT + fc * 8];
            #pragma unroll
            for (int j = 0; j < 8; ++j)
                acc[j] = fmaf(ww[u], bf2f(vv[j]), acc[j]);
        }
    }
    // reduce over sub (lanes differing in bits 3..5)
    #pragma unroll
    for (int m = 8; m < 64; m <<= 1)
        #pragma unroll
        for (int j = 0; j < 8; ++j)
            acc[j] += __shfl_xor(acc[j], m, 64);

    if (lane < 8) {   // lane w holds feats w*8 .. w*8+7 (fc==lane, sub==0)
        float dr = -dinv[r];
        size_t idx = (size_t)r * NOUT + lane * 8;
        float P[8];
        #pragma unroll
        for (int j = 0; j < 8; ++j) P[j] = dr * acc[j];
        if (mode == 0) {
            ushort8 v0 = *(const ushort8*)&vsrc[idx];
            ushort8 hout;
            #pragma unroll
            for (int j = 0; j < 8; ++j) {
                __bf16 h = (__bf16)P[j];
                hout[j] = *(unsigned short*)&h;
            }
            *(ushort8*)&tdst[idx] = hout;
            #pragma unroll
            for (int j = 0; j < 8; ++j)
                outacc[idx + j] = coe[0] * 0.5f * bf2f(v0[j]) + coe[1] * P[j];
        } else {
            ushort8 t0v = *(const ushort8*)&tdst[idx];
            ushort8 hout;
            float t2a[8];
            #pragma unroll
            for (int j = 0; j < 8; ++j) {
                float t2 = 2.0f * P[j] - bf2f(t0v[j]);
                t2a[j] = t2;
                __bf16 h = (__bf16)t2;
                hout[j] = *(unsigned short*)&h;
            }
            *(ushort8*)&tdst[idx] = hout;
            #pragma unroll
            for (int j = 0; j < 8; ++j)
                outacc[idx + j] += coe[ci] * t2a[j];
        }
    }
}

// ---------------- element-wise output convert ----------
__global__ void convert_kernel(const float* __restrict__ in, const int* __restrict__ flag,
                               void* __restrict__ out, int n) {
    int i = blockIdx.x * blockDim.x + threadIdx.x;
    bool isbf = flag[0] != 0;
    if (i < n) {
        float v = in[i];
        if (isbf) {
            __bf16 h = (__bf16)v;
            ((unsigned short*)out)[i] = *(unsigned short*)&h;
        } else {
            ((float*)out)[i] = v;
        }
    }
}

// ---------------- launch ----------------

extern "C" void kernel_launch(void* const* d_in, const int* in_sizes, int n_in,
                              void* d_out, int out_size, void* d_ws, size_t ws_size,
                              hipStream_t stream) {
    const void* feature = d_in[0];
    const void* W1      = d_in[1];
    const void* b1      = d_in[2];
    const void* W2      = d_in[3];
    const void* b2      = d_in[4];
    const void* temp    = d_in[5];
    const int* edge_index = (const int*)d_in[6];

    const int N = in_sizes[0] / NFEAT;   // 100000
    const int E = in_sizes[6] / 2;       // 3200000
    const int* row = edge_index;
    const int* col = edge_index + E;
    const int nb = (N + SCAN_CHUNK - 1) / SCAN_CHUNK;   // 49

    char* base = (char*)d_ws;
    size_t off = 0;
    auto alloc = [&](size_t bytes) -> char* {
        char* p = base + off;
        off = (off + bytes + 255) & ~(size_t)255;
        return p;
    };
    int*   flag   = (int*)  alloc(4);
    float* coe    = (float*)alloc(64);
    int*   bsum   = (int*)  alloc(256);
    int*   boff   = (int*)  alloc(256);
    int*   pbounds= (int*)  alloc(64);
    unsigned short* w1c = (unsigned short*)alloc((size_t)NHID * NFEAT * 2);
    float* b1c    = (float*)alloc(NHID * 4);
    unsigned short* w2c = (unsigned short*)alloc((size_t)NOUT * NHID * 2);
    float* b2c    = (float*)alloc(NOUT * 4);
    float* dinv   = (float*)alloc((size_t)N * 4);
    int*   deg    = (int*)  alloc((size_t)N * 4);
    int*   rowptr = (int*)  alloc((size_t)(N + 1) * 4);
    int*   cursor = (int*)  alloc((size_t)(N + 1) * 4);
    // overlay region R (N*NHID*2 = 51.2MB): xhid lives gemm1->gemm2; afterwards
    // colss (E*4 = 12.8MB) | outacc (N*NOUT*4 = 25.6MB) | wn (E*4 = 12.8MB) = 51.2MB.
    char*  R      = alloc((size_t)N * NHID * 2);
    unsigned short* xhid = (unsigned short*)R;
    int*   colss  = (int*)R;
    float* outacc = (float*)(R + (size_t)E * 4);
    float* wn     = (float*)(R + (size_t)E * 4 + (size_t)N * NOUT * 4);
    unsigned short* t_a = (unsigned short*)alloc((size_t)N * NOUT * 2);
    unsigned short* t_b = (unsigned short*)alloc((size_t)N * NOUT * 2);

    // dtype flag, coefficients, canonical weights
    detect_kernel<<<1, 64, 0, stream>>>((const unsigned short*)temp, flag);
    coef_kernel<<<1, 64, 0, stream>>>(temp, flag, coe);
    prep_weights<<<128, 256, 0, stream>>>(W1, b1, W2, b2, flag, w1c, b1c, w2c, b2c);

    // dense MLP (writes xhid, then t_a = Tx0 bf16, row-major)
    const int nbm = (N + 127) / 128;
    gemm_kernel<128, 2, true, true><<<dim3(nbm * 2), 256, 0, stream>>>(
        feature, w1c, b1c, flag, xhid, N, NFEAT, NHID);
    gemm_kernel<64, 1, false, false><<<dim3(nbm), 256, 0, stream>>>(
        xhid, w2c, b2c, flag, t_a, N, NHID, NOUT);

    // graph preprocessing (xhid dead now; colss/outacc/wn overlay it)
    hipMemsetAsync(deg, 0, (size_t)N * 4, stream);
    count_deg_kernel<<<(E + 255) / 256, 256, 0, stream>>>(row, deg, E);
    dinv_kernel<<<(N + 255) / 256, 256, 0, stream>>>(deg, dinv, N);
    partial_sum_kernel<<<nb, 256, 0, stream>>>(deg, bsum, N);
    scan_small_kernel<<<1, 64, 0, stream>>>(bsum, boff, rowptr, nb, N);
    scan_apply_kernel<<<nb, 256, 0, stream>>>(deg, boff, rowptr, cursor, N);
    part_bounds_kernel<<<1, 16, 0, stream>>>(rowptr, pbounds, N, E);
    {
        int nch = (E + 1023) / 1024;   // 4 edges/thread
        scatter_part_kernel<<<nch * 8, 256, 0, stream>>>(row, col, pbounds, cursor, colss, E);
    }
    wnorm_kernel<<<(E / 4 + 255) / 256, 256, 0, stream>>>(colss, dinv, wn, E);

    // Chebyshev propagation with 2 ping-pong bf16 buffers (row-major)
    int pb = (N + 3) / 4;
    prop_kernel<<<pb, 256, 0, stream>>>(t_a, t_b, outacc, rowptr, colss, wn, dinv, coe, 0, 0, N);
    unsigned short* src = t_b;
    unsigned short* dst = t_a;
    for (int i = 2; i <= K_ORDER; ++i) {
        prop_kernel<<<pb, 256, 0, stream>>>(src, dst, outacc, rowptr, colss, wn, dinv, coe, 1, i, N);
        unsigned short* tmp = src; src = dst; dst = tmp;
    }

    convert_kernel<<<(N * NOUT + 255) / 256, 256, 0, stream>>>(outacc, flag, d_out, N * NOUT);
}

// Round 9
// 1351.115 us; speedup vs baseline: 2.0271x; 1.0258x over previous
//
#include <hip/hip_runtime.h>

#define K_ORDER 10
#define NFEAT 512
#define NHID 256
#define NOUT 64
#define PI_F 3.14159265358979323846f
#define SCAN_CHUNK 2048
#define NRANGE 8
#define RSHIFT 14   // column range = c >> 14 (16384 cols -> 2MB vsrc window)

typedef __bf16 bf16x8 __attribute__((ext_vector_type(8)));
typedef unsigned short ushort8 __attribute__((ext_vector_type(8)));
typedef float f32x4 __attribute__((ext_vector_type(4)));

__device__ __forceinline__ float bf2f(unsigned short u) {
    union { unsigned int i; float f; } x;
    x.i = ((unsigned int)u) << 16;
    return x.f;
}

__device__ __forceinline__ unsigned short f2bfu(float f) {
    __bf16 h = (__bf16)f;
    return *(unsigned short*)&h;
}

#define GLOAD_LDS16(g, l) __builtin_amdgcn_global_load_lds( \
    (const __attribute__((address_space(1))) void*)(g),     \
    (__attribute__((address_space(3))) void*)(l), 16, 0, 0)

// ---------------- input dtype detection ----------------
__global__ void detect_kernel(const unsigned short* __restrict__ temp, int* __restrict__ flag) {
    if (threadIdx.x == 0 && blockIdx.x == 0) {
        int cnt = 0;
        for (int i = 0; i < K_ORDER + 1; ++i) {
            unsigned short s = temp[i];
            if (s >= 0x3E00 && s < 0x4080) cnt++;
        }
        flag[0] = (cnt >= 9) ? 1 : 0;
    }
}

// ---------------- weight canonicalization (bf16 W, f32 bias) ----------------
__global__ void prep_weights(const void* __restrict__ W1, const void* __restrict__ b1,
                             const void* __restrict__ W2, const void* __restrict__ b2,
                             const int* __restrict__ flag,
                             unsigned short* __restrict__ w1o, float* __restrict__ b1o,
                             unsigned short* __restrict__ w2o, float* __restrict__ b2o) {
    bool isbf = flag[0] != 0;
    int stride = gridDim.x * blockDim.x;
    int i0 = blockIdx.x * blockDim.x + threadIdx.x;
    const int n1 = NHID * NFEAT;
    const int n2 = NOUT * NHID;
    for (int i = i0; i < n1; i += stride)
        w1o[i] = isbf ? ((const unsigned short*)W1)[i] : f2bfu(((const float*)W1)[i]);
    for (int i = i0; i < n2; i += stride)
        w2o[i] = isbf ? ((const unsigned short*)W2)[i] : f2bfu(((const float*)W2)[i]);
    for (int i = i0; i < NHID; i += stride)
        b1o[i] = isbf ? bf2f(((const unsigned short*)b1)[i]) : ((const float*)b1)[i];
    for (int i = i0; i < NOUT; i += stride)
        b2o[i] = isbf ? bf2f(((const unsigned short*)b2)[i]) : ((const float*)b2)[i];
}

// ---------------- graph preprocessing ----------------
// Bin-level histogram: bin = row*8 + (col>>RSHIFT). Within-row range-grouping
// makes prop's vsrc gathers walk a ~2MB column window (L2-resident) instead of
// the full 12.8MB table (L3 random-gather ceiling ~3.9TB/s measured r7).

__global__ void countb_kernel(const int* __restrict__ row, const int* __restrict__ col,
                              int* __restrict__ degb, int e) {
    int i = blockIdx.x * blockDim.x + threadIdx.x;
    if (i < e) atomicAdd(&degb[(size_t)row[i] * NRANGE + (col[i] >> RSHIFT)], 1);
}

// deg[r] = sum of row's 8 bins; dinv = rsqrt(deg)
__global__ void sumdeg_kernel(const int* __restrict__ degb, int* __restrict__ deg,
                              float* __restrict__ dinv, int n) {
    int r = blockIdx.x * blockDim.x + threadIdx.x;
    if (r < n) {
        int4 a = *(const int4*)&degb[(size_t)r * NRANGE];
        int4 b = *(const int4*)&degb[(size_t)r * NRANGE + 4];
        int d = a.x + a.y + a.z + a.w + b.x + b.y + b.z + b.w;
        deg[r] = d;
        dinv[r] = (d > 0) ? rsqrtf((float)d) : 0.0f;
    }
}

__global__ __launch_bounds__(256) void partial_sum_kernel(const int* __restrict__ deg,
                                                          int* __restrict__ bsum, int n) {
    __shared__ int ws[4];
    int b = blockIdx.x, t = threadIdx.x;
    int base = b * SCAN_CHUNK + t * 8;
    int s = 0;
    #pragma unroll
    for (int j = 0; j < 8; ++j) { int i = base + j; if (i < n) s += deg[i]; }
    #pragma unroll
    for (int m = 1; m < 64; m <<= 1) s += __shfl_xor(s, m, 64);
    if ((t & 63) == 0) ws[t >> 6] = s;
    __syncthreads();
    if (t == 0) bsum[b] = ws[0] + ws[1] + ws[2] + ws[3];
}

// 1 block, 64 threads; nb <= 64
__global__ void scan_small_kernel(const int* __restrict__ bsum, int* __restrict__ boff,
                                  int* __restrict__ rowptr, int nb, int n) {
    int t = threadIdx.x;
    int v = (t < nb) ? bsum[t] : 0;
    int x = v;
    #pragma unroll
    for (int m = 1; m < 64; m <<= 1) { int y = __shfl_up(x, m, 64); if (t >= m) x += y; }
    if (t < nb) boff[t] = x - v;
    if (t == 63) rowptr[n] = x;
}

__global__ __launch_bounds__(256) void scan_apply_kernel(const int* __restrict__ deg,
                                                         const int* __restrict__ boff,
                                                         int* __restrict__ rowptr,
                                                         int* __restrict__ cursor, int n) {
    __shared__ int wtot[4];
    __shared__ int woff_s[4];
    int b = blockIdx.x, t = threadIdx.x;
    int lane = t & 63, wid = t >> 6;
    int base = b * SCAN_CHUNK + t * 8;
    int v[8], s[8];
    int run = 0;
    #pragma unroll
    for (int j = 0; j < 8; ++j) {
        int i = base + j;
        v[j] = (i < n) ? deg[i] : 0;
        run += v[j];
        s[j] = run;
    }
    int tsum = run;
    int x = tsum;
    #pragma unroll
    for (int m = 1; m < 64; m <<= 1) { int y = __shfl_up(x, m, 64); if (lane >= m) x += y; }
    int texcl = x - tsum;
    if (lane == 63) wtot[wid] = x;
    __syncthreads();
    if (t == 0) {
        int r = 0;
        #pragma unroll
        for (int w = 0; w < 4; ++w) { woff_s[w] = r; r += wtot[w]; }
    }
    __syncthreads();
    int ebase = boff[b] + woff_s[wid] + texcl;
    #pragma unroll
    for (int j = 0; j < 8; ++j) {
        int i = base + j;
        if (i < n) { int ex = ebase + s[j] - v[j]; rowptr[i] = ex; cursor[i] = ex; }
    }
}

// per-row 8-bin exclusive prefix from rowptr base -> bin cursors
__global__ void binoff_kernel(const int* __restrict__ degb, const int* __restrict__ rowptr,
                              int* __restrict__ cursor_b, int n) {
    int r = blockIdx.x * blockDim.x + threadIdx.x;
    if (r >= n) return;
    int4 a = *(const int4*)&degb[(size_t)r * NRANGE];
    int4 b = *(const int4*)&degb[(size_t)r * NRANGE + 4];
    int run = rowptr[r];
    int4 o0, o1;
    o0.x = run; run += a.x;
    o0.y = run; run += a.y;
    o0.z = run; run += a.z;
    o0.w = run; run += a.w;
    o1.x = run; run += b.x;
    o1.y = run; run += b.y;
    o1.z = run; run += b.z;
    o1.w = run;
    *(int4*)&cursor_b[(size_t)r * NRANGE] = o0;
    *(int4*)&cursor_b[(size_t)r * NRANGE + 4] = o1;
}

// ---- partition bounds: split row space into 8 equal-edge ranges via rowptr ----
__global__ void part_bounds_kernel(const int* __restrict__ rowptr, int* __restrict__ pb,
                                   int n, int e) {
    int j = threadIdx.x;
    if (j > 8) return;
    if (j == 8) { pb[8] = n; return; }
    long target = (long)j * e / 8;
    int lo = 0, hi = n;
    while (lo < hi) {
        int mid = (lo + hi) >> 1;
        if ((long)rowptr[mid] < target) lo = mid + 1; else hi = mid;
    }
    pb[j] = lo;
}

// ---- XCD-partitioned scatter (r6 structure) with bin key + (col,dinv) payload ----
__global__ __launch_bounds__(256) void scatter_part_kernel(
    const int* __restrict__ row, const int* __restrict__ col,
    const int* __restrict__ pbounds, const float* __restrict__ dinv,
    int* __restrict__ cursor_b, int2* __restrict__ pairs, int e) {
    const int j = blockIdx.x & 7;
    const int lo = pbounds[j], hi = pbounds[j + 1];
    const int base = ((blockIdx.x >> 3) * 256 + threadIdx.x) * 4;
    if (base + 3 < e) {
        int4 r4 = *(const int4*)(row + base);
        int4 c4 = *(const int4*)(col + base);
        #pragma unroll
        for (int k = 0; k < 4; ++k) {
            int r = (&r4.x)[k];
            if (r >= lo && r < hi) {
                int c = (&c4.x)[k];
                int p = atomicAdd(&cursor_b[(size_t)r * NRANGE + (c >> RSHIFT)], 1);
                pairs[p] = make_int2(c, __float_as_int(dinv[c]));
            }
        }
    } else {
        for (int k = 0; k < 4; ++k) {
            int i = base + k;
            if (i < e) {
                int r = row[i];
                if (r >= lo && r < hi) {
                    int c = col[i];
                    int p = atomicAdd(&cursor_b[(size_t)r * NRANGE + (c >> RSHIFT)], 1);
                    pairs[p] = make_int2(c, __float_as_int(dinv[c]));
                }
            }
        }
    }
}

// ---------------- Chebyshev coefficients ----------------

__global__ void coef_kernel(const void* __restrict__ temp, const int* __restrict__ flag,
                            float* __restrict__ coe) {
    int i = threadIdx.x;
    bool isbf = flag[0] != 0;
    if (i <= K_ORDER) {
        float s = 0.0f;
        #pragma unroll
        for (int j = 0; j <= K_ORDER; ++j) {
            float t = isbf ? bf2f(((const unsigned short*)temp)[j]) : ((const float*)temp)[j];
            t = fmaxf(t, 0.0f);
            float theta = ((float)(K_ORDER - j) + 0.5f) * PI_F / (float)(K_ORDER + 1);
            s += cosf((float)i * theta) * t;
        }
        coe[i] = (2.0f / (float)(K_ORDER + 1)) * s;
    }
}

// ---------------- MFMA GEMM: global_load_lds staging + 2-phase pipeline ----------------

template<int BN, int NBY, bool RELU, bool A_FLAGGED>
__global__ __launch_bounds__(256) void gemm_kernel(
    const void* __restrict__ A, const unsigned short* __restrict__ Bw,
    const float* __restrict__ bias, const int* __restrict__ flag,
    unsigned short* __restrict__ C, int M, int Kdim, int ldc)
{
    constexpr int BM = 128, BK = 32;
    constexpr int FN = BN / 32;
    constexpr int ABUF = A_FLAGGED ? (BM * BK * 4) : (BM * BK * 2);
    constexpr int BBUF = BN * BK * 2;
    __shared__ char lds[2 * ABUF + 2 * BBUF] __attribute__((aligned(16)));

    const int tid = threadIdx.x;
    const int lane = tid & 63, wid = tid >> 6;
    const int bid = blockIdx.x;
    const int by = bid % NBY;
    const int bx = bid / NBY;
    const int row0 = bx * BM;
    const int col0 = by * BN;
    const int wrow = (wid >> 1) * (BM / 2);
    const int wcol = (wid & 1) * (BN / 2);
    const bool af32 = A_FLAGGED ? (flag[0] == 0) : false;

    char* ldsA0 = lds;
    char* ldsB0 = lds + 2 * ABUF;

    auto stage = [&](int buf, int k0) {
        {
            constexpr int PW = (BBUF / 1024) / 4;
            #pragma unroll
            for (int rr = 0; rr < PW; ++rr) {
                int q = rr * 4 + wid;
                int off = q * 1024 + lane * 16;
                int brow = off >> 6;
                int scol = ((off >> 4) & 3) ^ (brow & 3);
                const char* src = (const char*)Bw + (((size_t)(col0 + brow) * Kdim + k0) << 1) + scol * 16;
                GLOAD_LDS16(src, ldsB0 + buf * BBUF + q * 1024);
            }
        }
        if (af32) {
            #pragma unroll
            for (int rr = 0; rr < 4; ++rr) {
                int q = rr * 4 + wid;
                int off = q * 1024 + lane * 16;
                int arow = off >> 7;
                int scol = ((off >> 4) & 7) ^ (arow & 7);
                int grow = row0 + arow; if (grow >= M) grow = M - 1;
                const char* src = (const char*)A + (((size_t)grow * Kdim + k0) << 2) + scol * 16;
                GLOAD_LDS16(src, ldsA0 + buf * ABUF + q * 1024);
            }
        } else {
            #pragma unroll
            for (int rr = 0; rr < 2; ++rr) {
                int q = rr * 4 + wid;
                int off = q * 1024 + lane * 16;
                int arow = off >> 6;
                int scol = ((off >> 4) & 3) ^ (arow & 3);
                int grow = row0 + arow; if (grow >= M) grow = M - 1;
                const char* src = (const char*)A + (((size_t)grow * Kdim + k0) << 1) + scol * 16;
                GLOAD_LDS16(src, ldsA0 + buf * ABUF + q * 1024);
            }
        }
    };

    f32x4 acc[4][FN] = {};

    auto compute = [&](int buf) {
        const char* Ab = ldsA0 + buf * ABUF;
        const char* Bb = ldsB0 + buf * BBUF;
        const int kq = lane >> 4;
        bf16x8 af[4];
        if (af32) {
            #pragma unroll
            for (int mi = 0; mi < 4; ++mi) {
                int aRow = wrow + mi * 16 + (lane & 15);
                int base = aRow * 128 + kq * 32;
                int sw = (aRow & 7) << 4;
                f32x4 lo = *(const f32x4*)(Ab + (base ^ sw));
                f32x4 hi = *(const f32x4*)(Ab + ((base + 16) ^ sw));
                #pragma unroll
                for (int j = 0; j < 4; ++j) { af[mi][j] = (__bf16)lo[j]; af[mi][j + 4] = (__bf16)hi[j]; }
            }
        } else {
            #pragma unroll
            for (int mi = 0; mi < 4; ++mi) {
                int aRow = wrow + mi * 16 + (lane & 15);
                int o = (aRow * 64 + kq * 16) ^ ((aRow & 3) << 4);
                af[mi] = *(const bf16x8*)(Ab + o);
            }
        }
        bf16x8 bfv[FN];
        #pragma unroll
        for (int ni = 0; ni < FN; ++ni) {
            int bRow = wcol + ni * 16 + (lane & 15);
            int o = (bRow * 64 + kq * 16) ^ ((bRow & 3) << 4);
            bfv[ni] = *(const bf16x8*)(Bb + o);
        }
        #pragma unroll
        for (int mi = 0; mi < 4; ++mi)
            #pragma unroll
            for (int ni = 0; ni < FN; ++ni)
                acc[mi][ni] = __builtin_amdgcn_mfma_f32_16x16x32_bf16(af[mi], bfv[ni],
                                                                      acc[mi][ni], 0, 0, 0);
    };

    const int NT = Kdim / BK;
    stage(0, 0);
    __syncthreads();
    int buf = 0;
    for (int t = 0; t < NT; ++t) {
        if (t + 1 < NT) stage(buf ^ 1, (t + 1) * BK);
        compute(buf);
        __syncthreads();
        buf ^= 1;
    }

    #pragma unroll
    for (int mi = 0; mi < 4; ++mi) {
        #pragma unroll
        for (int ni = 0; ni < FN; ++ni) {
            #pragma unroll
            for (int rg = 0; rg < 4; ++rg) {
                int grow = row0 + wrow + mi * 16 + (lane >> 4) * 4 + rg;
                int gcol = col0 + wcol + ni * 16 + (lane & 15);
                if (grow < M) {
                    float vv = acc[mi][ni][rg] + bias[gcol];
                    if (RELU) vv = fmaxf(vv, 0.0f);
                    C[(size_t)grow * ldc + gcol] = f2bfu(vv);
                }
            }
        }
    }
}

// ---------------- Chebyshev propagation ----------------
// Round-0 structure (wave per row, sub=lane>>3 edge slot, fc=lane&7 feat chunk).
// Edges are range-grouped within each row (scatter bin key) so the vsrc gather
// window per co-resident cohort is ~2MB -> L2-served. Payload is fused int2
// (col, dinv[col]). Epilogue verbatim from round 0.

__global__ __launch_bounds__(256) void prop_kernel(const unsigned short* __restrict__ vsrc,
                                                   unsigned short* __restrict__ tdst,
                                                   float* __restrict__ outacc,
                                                   const int* __restrict__ rowptr,
                                                   const int2* __restrict__ pairs,
                                                   const float* __restrict__ dinv,
                                                   const float* __restrict__ coe,
                                                   int mode, int ci, int n) {
    int lane = threadIdx.x & 63;
    int r = blockIdx.x * 4 + (threadIdx.x >> 6);
    if (r >= n) return;
    int fc = lane & 7;
    int sub = lane >> 3;
    int e0 = rowptr[r], e1 = rowptr[r + 1];
    float acc[8] = {};
    for (int e = e0; e < e1; e += 32) {
        int cc[4]; float ww[4];
        #pragma unroll
        for (int u = 0; u < 4; ++u) {
            int ee = e + u * 8 + sub;
            bool valid = ee < e1;
            int2 pr = valid ? pairs[ee] : make_int2(0, 0);
            cc[u] = pr.x;
            ww[u] = __int_as_float(pr.y);
        }
        #pragma unroll
        for (int u = 0; u < 4; ++u) {
            ushort8 vv = *(const ushort8*)&vsrc[(size_t)cc[u] * NOUT + fc * 8];
            #pragma unroll
            for (int j = 0; j < 8; ++j)
                acc[j] = fmaf(ww[u], bf2f(vv[j]), acc[j]);
        }
    }
    // reduce over sub (lanes differing in bits 3..5)
    #pragma unroll
    for (int m = 8; m < 64; m <<= 1)
        #pragma unroll
        for (int j = 0; j < 8; ++j)
            acc[j] += __shfl_xor(acc[j], m, 64);

    if (lane < 8) {   // lane w holds feats w*8 .. w*8+7 (fc==lane, sub==0)
        float dr = -dinv[r];
        size_t idx = (size_t)r * NOUT + lane * 8;
        float P[8];
        #pragma unroll
        for (int j = 0; j < 8; ++j) P[j] = dr * acc[j];
        if (mode == 0) {
            ushort8 v0 = *(const ushort8*)&vsrc[idx];
            ushort8 hout;
            #pragma unroll
            for (int j = 0; j < 8; ++j) {
                __bf16 h = (__bf16)P[j];
                hout[j] = *(unsigned short*)&h;
            }
            *(ushort8*)&tdst[idx] = hout;
            #pragma unroll
            for (int j = 0; j < 8; ++j)
                outacc[idx + j] = coe[0] * 0.5f * bf2f(v0[j]) + coe[1] * P[j];
        } else {
            ushort8 t0v = *(const ushort8*)&tdst[idx];
            ushort8 hout;
            float t2a[8];
            #pragma unroll
            for (int j = 0; j < 8; ++j) {
                float t2 = 2.0f * P[j] - bf2f(t0v[j]);
                t2a[j] = t2;
                __bf16 h = (__bf16)t2;
                hout[j] = *(unsigned short*)&h;
            }
            *(ushort8*)&tdst[idx] = hout;
            #pragma unroll
            for (int j = 0; j < 8; ++j)
                outacc[idx + j] += coe[ci] * t2a[j];
        }
    }
}

// ---------------- element-wise output convert ----------
__global__ void convert_kernel(const float* __restrict__ in, const int* __restrict__ flag,
                               void* __restrict__ out, int n) {
    int i = blockIdx.x * blockDim.x + threadIdx.x;
    bool isbf = flag[0] != 0;
    if (i < n) {
        float v = in[i];
        if (isbf) {
            __bf16 h = (__bf16)v;
            ((unsigned short*)out)[i] = *(unsigned short*)&h;
        } else {
            ((float*)out)[i] = v;
        }
    }
}

// ---------------- launch ----------------

extern "C" void kernel_launch(void* const* d_in, const int* in_sizes, int n_in,
                              void* d_out, int out_size, void* d_ws, size_t ws_size,
                              hipStream_t stream) {
    const void* feature = d_in[0];
    const void* W1      = d_in[1];
    const void* b1      = d_in[2];
    const void* W2      = d_in[3];
    const void* b2      = d_in[4];
    const void* temp    = d_in[5];
    const int* edge_index = (const int*)d_in[6];

    const int N = in_sizes[0] / NFEAT;   // 100000
    const int E = in_sizes[6] / 2;       // 3200000
    const int* row = edge_index;
    const int* col = edge_index + E;
    const int nb = (N + SCAN_CHUNK - 1) / SCAN_CHUNK;   // 49
    const int nbin = N * NRANGE;

    char* base = (char*)d_ws;
    size_t off = 0;
    auto alloc = [&](size_t bytes) -> char* {
        char* p = base + off;
        off = (off + bytes + 255) & ~(size_t)255;
        return p;
    };
    int*   flag   = (int*)  alloc(4);
    float* coe    = (float*)alloc(64);
    int*   bsum   = (int*)  alloc(256);
    int*   boff   = (int*)  alloc(256);
    int*   pbounds= (int*)  alloc(64);
    unsigned short* w1c = (unsigned short*)alloc((size_t)NHID * NFEAT * 2);
    float* b1c    = (float*)alloc(NHID * 4);
    unsigned short* w2c = (unsigned short*)alloc((size_t)NOUT * NHID * 2);
    float* b2c    = (float*)alloc(NOUT * 4);
    float* dinv   = (float*)alloc((size_t)N * 4);
    int*   deg    = (int*)  alloc((size_t)N * 4);
    int*   rowptr = (int*)  alloc((size_t)(N + 1) * 4);
    int*   cursor = (int*)  alloc((size_t)(N + 1) * 4);
    int*   degb   = (int*)  alloc((size_t)nbin * 4);        // 3.2MB
    int*   cursor_b = (int*)alloc((size_t)nbin * 4);        // 3.2MB
    // overlay region R (N*NHID*2 = 51.2MB): xhid lives gemm1->gemm2; afterwards
    // pairs (E*8 = 25.6MB) | outacc (N*NOUT*4 = 25.6MB) = 51.2MB.
    char*  R      = alloc((size_t)N * NHID * 2);
    unsigned short* xhid = (unsigned short*)R;
    int2*  pairs  = (int2*)R;
    float* outacc = (float*)(R + (size_t)E * 8);
    unsigned short* t_a = (unsigned short*)alloc((size_t)N * NOUT * 2);
    unsigned short* t_b = (unsigned short*)alloc((size_t)N * NOUT * 2);

    // dtype flag, coefficients, canonical weights
    detect_kernel<<<1, 64, 0, stream>>>((const unsigned short*)temp, flag);
    coef_kernel<<<1, 64, 0, stream>>>(temp, flag, coe);
    prep_weights<<<128, 256, 0, stream>>>(W1, b1, W2, b2, flag, w1c, b1c, w2c, b2c);

    // dense MLP (writes xhid, then t_a = Tx0 bf16, row-major)
    const int nbm = (N + 127) / 128;
    gemm_kernel<128, 2, true, true><<<dim3(nbm * 2), 256, 0, stream>>>(
        feature, w1c, b1c, flag, xhid, N, NFEAT, NHID);
    gemm_kernel<64, 1, false, false><<<dim3(nbm), 256, 0, stream>>>(
        xhid, w2c, b2c, flag, t_a, N, NHID, NOUT);

    // graph preprocessing (xhid dead now; pairs/outacc overlay it)
    hipMemsetAsync(degb, 0, (size_t)nbin * 4, stream);
    countb_kernel<<<(E + 255) / 256, 256, 0, stream>>>(row, col, degb, E);
    sumdeg_kernel<<<(N + 255) / 256, 256, 0, stream>>>(degb, deg, dinv, N);
    partial_sum_kernel<<<nb, 256, 0, stream>>>(deg, bsum, N);
    scan_small_kernel<<<1, 64, 0, stream>>>(bsum, boff, rowptr, nb, N);
    scan_apply_kernel<<<nb, 256, 0, stream>>>(deg, boff, rowptr, cursor, N);
    binoff_kernel<<<(N + 255) / 256, 256, 0, stream>>>(degb, rowptr, cursor_b, N);
    part_bounds_kernel<<<1, 16, 0, stream>>>(rowptr, pbounds, N, E);
    {
        int nch = (E + 1023) / 1024;   // 4 edges/thread
        scatter_part_kernel<<<nch * 8, 256, 0, stream>>>(row, col, pbounds, dinv,
                                                         cursor_b, pairs, E);
    }

    // Chebyshev propagation with 2 ping-pong bf16 buffers (row-major)
    int pb = (N + 3) / 4;
    prop_kernel<<<pb, 256, 0, stream>>>(t_a, t_b, outacc, rowptr, pairs, dinv, coe, 0, 0, N);
    unsigned short* src = t_b;
    unsigned short* dst = t_a;
    for (int i = 2; i <= K_ORDER; ++i) {
        prop_kernel<<<pb, 256, 0, stream>>>(src, dst, outacc, rowptr, pairs, dinv, coe, 1, i, N);
        unsigned short* tmp = src; src = dst; dst = tmp;
    }

    convert_kernel<<<(N * NOUT + 255) / 256, 256, 0, stream>>>(outacc, flag, d_out, N * NOUT);
}